// Round 6
// baseline (613.421 us; speedup 1.0000x reference)
//
#include <hip/hip_runtime.h>
#include <hip/hip_bf16.h>

#define BATCH 8
#define N1 4096
#define N2 2048
#define HID 64
#define KNN 8
#define INDIM 10

using u64 = unsigned long long;
using bf16 = __hip_bfloat16;
typedef __attribute__((ext_vector_type(8))) short short8;
typedef __attribute__((ext_vector_type(4))) float f32x4;

// Scratch in static device memory (~115 MB): d_ws size is not guaranteed.
// Every buffer is fully rewritten each call (or re-initialized by init_kernel).
__device__ __align__(256) float    g_h1[BATCH * N1 * HID];
__device__ __align__(256) float    g_h2[BATCH * N2 * HID];
__device__ __align__(256) float    g_x2n[BATCH * N1];
__device__ __align__(256) float    g_x2n2[BATCH * N2];
__device__ __align__(256) int      g_nbr[BATCH * N1 * KNN];
__device__ __align__(256) float    g_uu[BATCH * N1 * 96];
__device__ __align__(256) float    g_vv[BATCH * N1 * 96];
__device__ __align__(256) unsigned g_ek1[BATCH * N1 * HID];
__device__ __align__(256) unsigned g_ek2[BATCH * N2 * HID];
// 3-way bf16 split of h in MFMA FRAGMENT-MAJOR layout (kNN):
// [tile16][chunk(2)][q(4)][c(16)][j(8)] shorts; node i=tile*16+c.
__device__ __align__(256) short    g_f1[BATCH * N1 * HID];
__device__ __align__(256) short    g_f2[BATCH * N1 * HID];
__device__ __align__(256) short    g_f3[BATCH * N1 * HID];
// frag-major f32 copies of u,v for edge MFMA A-prep:
// [tile16][kc(3)][q(4)][c(16)][j(8)] floats, node = tile*16+c, kk=kc*32+q*8+j.
__device__ __align__(256) float    g_uf[BATCH * N1 * 96];
__device__ __align__(256) float    g_vf[BATCH * N1 * 96];
// 2-way bf16 split W2 fragments: [level][no(4)][kc(3)][lane(64)][j(8)]
__device__ __align__(256) short    g_wf1[2 * 4 * 3 * 64 * 8];
__device__ __align__(256) short    g_wf2[2 * 4 * 3 * 64 * 8];

__device__ __forceinline__ float eluf(float x) { return x > 0.f ? x : __expf(x) - 1.f; }
// order-isomorphic float->u32 encoding: a<b  <=>  enc(a)<enc(b) (unsigned)
__device__ __forceinline__ unsigned encf(float f) {
  unsigned u = __float_as_uint(f);
  return u ^ ((unsigned)((int)u >> 31) | 0x80000000u);
}
__device__ __forceinline__ float decf(unsigned k) {
  unsigned u = (k & 0x80000000u) ? (k & 0x7FFFFFFFu) : ~k;
  return __uint_as_float(u);
}
// encf(-1.0f): ELU outputs are strictly > -1 => legal max-identity.
#define ENC_NEG1 0x407FFFFFu
__device__ __forceinline__ unsigned enc_safe(float v) {
  if (!(v == v)) return ENC_NEG1;
  return encf(v);
}
__device__ __forceinline__ float dec_safe(unsigned k) {
  float v = decf(k);
  if (!(v == v)) return -1.0f;
  return fminf(fmaxf(v, -3.0e38f), 3.0e38f);
}
// v_med3_u32: median of three u32. Inserting x into a SORTED ascending list a:
// r[i] = med3(a[i-1], a[i], x)  (r[0] = min(a[0], x)) -- 8 independent ops,
// half the op count of the min/max bubble and no serial dep chain.
__device__ __forceinline__ unsigned umed3(unsigned a, unsigned b, unsigned c) {
  unsigned d;
  asm("v_med3_u32 %0, %1, %2, %3" : "=v"(d) : "v"(a), "v"(b), "v"(c));
  return d;
}
// 3-way bf16 split: v ~= b1 + b2 + b3 (error ~2^-25 relative)
__device__ __forceinline__ void split3(float v, short& b1, short& b2, short& b3) {
  bf16 x1 = __float2bfloat16(v);
  float r1 = v - __bfloat162float(x1);
  bf16 x2 = __float2bfloat16(r1);
  float r2 = r1 - __bfloat162float(x2);
  bf16 x3 = __float2bfloat16(r2);
  b1 = *(short*)&x1; b2 = *(short*)&x2; b3 = *(short*)&x3;
}
// 2-way bf16 split
__device__ __forceinline__ void split2(float v, short& b1, short& b2) {
  bf16 x1 = __float2bfloat16(v);
  float r1 = v - __bfloat162float(x1);
  bf16 x2 = __float2bfloat16(r1);
  b1 = *(short*)&x1; b2 = *(short*)&x2;
}
// write one node's 64 splits into kNN fragment-major layout
__device__ __forceinline__ void store_frags(int node, const short* s1,
                                            const short* s2, const short* s3) {
  size_t tb = ((size_t)(node >> 4)) * 1024 + (node & 15) * 8;
#pragma unroll
  for (int chunk = 0; chunk < 2; ++chunk) {
#pragma unroll
    for (int q = 0; q < 4; ++q) {
      size_t a = tb + chunk * 512 + q * 128;
      int k = chunk * 32 + q * 8;
      *(short8*)(g_f1 + a) = *(const short8*)(s1 + k);
      *(short8*)(g_f2 + a) = *(const short8*)(s2 + k);
      *(short8*)(g_f3 + a) = *(const short8*)(s3 + k);
    }
  }
}
// elu(a+b) for 8 floats -> 2-way split short8 frags
__device__ __forceinline__ void tv_frag(float4 a0, float4 a1, float4 b0,
                                        float4 b1, short8& s1, short8& s2) {
  float v[8] = {a0.x + b0.x, a0.y + b0.y, a0.z + b0.z, a0.w + b0.w,
                a1.x + b1.x, a1.y + b1.y, a1.z + b1.z, a1.w + b1.w};
#pragma unroll
  for (int e = 0; e < 8; ++e) {
    float t = eluf(v[e]);
    short p1, p2;
    split2(t, p1, p2);
    s1[e] = p1; s2[e] = p2;
  }
}

// ---------------- init the scatter-max accumulators --------------------------
__global__ __launch_bounds__(256) void init_kernel() {
  int t = blockIdx.x * 256 + threadIdx.x;
  uint4 z = make_uint4(ENC_NEG1, ENC_NEG1, ENC_NEG1, ENC_NEG1);
  const int n1 = BATCH * N1 * HID / 4;
  if (t < n1) ((uint4*)g_ek1)[t] = z;
  else ((uint4*)g_ek2)[t - n1] = z;
}

// ---------------- W2 -> 2-way-split MFMA B-fragments (once per launch) -------
__global__ __launch_bounds__(256) void wfrag_kernel(const float* __restrict__ w1,
                                                    const float* __restrict__ w2) {
  int level = blockIdx.x;
  const float* w = level ? w2 : w1;
  for (int idx = threadIdx.x; idx < 6144; idx += 256) {
    int no = idx / 1536;
    int rem = idx - no * 1536;
    int kc = rem / 512;
    int rem2 = rem - kc * 512;
    int lane = rem2 >> 3;
    int j = rem2 & 7;
    int k = kc * 32 + (lane >> 4) * 8 + j;
    int o = no * 16 + (lane & 15);
    short b1, b2;
    split2(w[k * 64 + o], b1, b2);
    g_wf1[level * 6144 + idx] = b1;
    g_wf2[level * 6144 + idx] = b2;
  }
}

// ---------------- input MLP: x*norm -> 32 (elu) -> 64 (elu) + |h|^2 + splits -
__global__ __launch_bounds__(256) void input_mlp(
    const float* __restrict__ x, const float* __restrict__ norm,
    const float* __restrict__ w1g, const float* __restrict__ b1g,
    const float* __restrict__ w2g, const float* __restrict__ b2g) {
  __shared__ float sw1[320], sb1[32], sw2[2048], sb2[64], snorm[INDIM];
  int t = threadIdx.x;
  for (int q = t; q < 320; q += 256) sw1[q] = w1g[q];
  for (int q = t; q < 2048; q += 256) sw2[q] = w2g[q];
  if (t < 32) sb1[t] = b1g[t];
  if (t < 64) sb2[t] = b2g[t];
  if (t < INDIM) snorm[t] = norm[t];
  __syncthreads();
  int node = blockIdx.x * 256 + t;  // < BATCH*N1
  float xv[INDIM];
#pragma unroll
  for (int d = 0; d < INDIM; ++d)
    xv[d] = x[(size_t)node * INDIM + d] * snorm[d];
  float t1[32];
#pragma unroll
  for (int c = 0; c < 32; ++c) {
    float acc = sb1[c];
#pragma unroll
    for (int d = 0; d < INDIM; ++d) acc += xv[d] * sw1[d * 32 + c];
    t1[c] = eluf(acc);
  }
  float* hr = g_h1 + (size_t)node * HID;
  float sq = 0.f;
  short s1l[HID], s2l[HID], s3l[HID];
#pragma unroll
  for (int c = 0; c < HID; ++c) {
    float acc = sb2[c];
#pragma unroll
    for (int d = 0; d < 32; ++d) acc += t1[d] * sw2[d * HID + c];
    float v = eluf(acc);
    hr[c] = v;
    sq += v * v;
    split3(v, s1l[c], s2l[c], s3l[c]);
  }
  store_frags(node, s1l, s2l, s3l);
  g_x2n[node] = sq;
}

// ---------------- MFMA Gram-matrix kNN (k=8), u32-key med3 selection ---------
// r26: occupancy via GRID, not block width. r25 proved a 74 KB / 512-thread
// block pins to 1 block/CU (21% occ, dur regressed). Here: 256-thread block
// = ONE 32-row strip (NSET=2), its 4 waves split columns into QUARTERS;
// grid doubles to 8*(N1/32)=1024 -> 4 blocks/CU x 4 waves = 16 waves/CU
// (50%) at UNCHANGED total B-fragment L2 traffic (4096 waves x 64 tiles x
// 6 KB = 1.57 GB = r24). LDS: per-pass 16 rows x 64 lists x 9 u32, stride
// 577 (odd -> <=2-way banks) = 36.9 KB; 4 x 36.9 = 147.7 <= 160 KB.
// launch_bounds(256,2): r23 showed (256,4) caps the allocator at 64 VGPR
// and spills (21 MB scratch writes); (256,2) gives ~88 VGPR no-spill and
// still PERMITS 4 waves/SIMD at 88 <= 128.
template <int LEVEL>
__global__ __launch_bounds__(256, 2) void knn_kernel() {
  constexpr int n = LEVEL ? N2 : N1;
  constexpr int NT = n / 16;           // column tiles in batch
  constexpr int QT = NT / 4;           // tiles per column quarter
  constexpr int NSET = LEVEL ? 1 : 2;  // 16-row A-tiles per block
  constexpr int ROWS = NSET * 16;      // rows per block
  __shared__ unsigned lm[16 * 577];    // 36,928 B (one 16-row pass)

  int b = blockIdx.x & 7;              // XCD-friendly batch swizzle
  int rb = (blockIdx.x >> 3) * ROWS;
  int t = threadIdx.x;
  int wv = t >> 6, lane = t & 63;      // wv = column quarter
  int q = lane >> 4, c = lane & 15;
  const float* __restrict__ x2b = (LEVEL ? g_x2n2 : g_x2n) + (size_t)b * n;
  size_t abase = ((size_t)((b * n + rb) >> 4)) * 1024 + lane * 8;
  short8 A1a[NSET], A1b[NSET], A2a[NSET], A2b[NSET], A3a[NSET], A3b[NSET];
#pragma unroll
  for (int e = 0; e < NSET; ++e) {
    size_t ab = abase + (size_t)e * 1024;
    A1a[e] = *(const short8*)(g_f1 + ab);
    A1b[e] = *(const short8*)(g_f1 + ab + 512);
    A2a[e] = *(const short8*)(g_f2 + ab);
    A2b[e] = *(const short8*)(g_f2 + ab + 512);
    A3a[e] = *(const short8*)(g_f3 + ab);
    A3b[e] = *(const short8*)(g_f3 + ab + 512);
  }
  unsigned best[NSET][4][KNN];
#pragma unroll
  for (int e = 0; e < NSET; ++e)
#pragma unroll
    for (int r = 0; r < 4; ++r)
#pragma unroll
      for (int p = 0; p < KNN; ++p) best[e][r][p] = 0xFFFFFFFFu;
  const int ct0 = wv * QT;
  const int selftile = rb >> 4;        // + e = only tile with cb==i
  const f32x4 zero = {0.f, 0.f, 0.f, 0.f};
  size_t bb = ((size_t)(b * n) >> 4) * 1024 + (size_t)ct0 * 1024 + lane * 8;
  for (int ct = ct0; ct < ct0 + QT; ++ct, bb += 1024) {
    short8 B1a = *(const short8*)(g_f1 + bb);
    short8 B1b = *(const short8*)(g_f1 + bb + 512);
    short8 B2a = *(const short8*)(g_f2 + bb);
    short8 B2b = *(const short8*)(g_f2 + bb + 512);
    short8 B3a = *(const short8*)(g_f3 + bb);
    short8 B3b = *(const short8*)(g_f3 + bb + 512);
    float x2c = x2b[ct * 16 + c];
#pragma unroll
    for (int e = 0; e < NSET; ++e) {
      f32x4 acc0 = __builtin_amdgcn_mfma_f32_16x16x32_bf16(A1a[e], B1a, zero, 0, 0, 0);
      f32x4 acc1 = __builtin_amdgcn_mfma_f32_16x16x32_bf16(A1b[e], B1b, zero, 0, 0, 0);
      acc0 = __builtin_amdgcn_mfma_f32_16x16x32_bf16(A1a[e], B2a, acc0, 0, 0, 0);
      acc1 = __builtin_amdgcn_mfma_f32_16x16x32_bf16(A1b[e], B2b, acc1, 0, 0, 0);
      acc0 = __builtin_amdgcn_mfma_f32_16x16x32_bf16(A2a[e], B1a, acc0, 0, 0, 0);
      acc1 = __builtin_amdgcn_mfma_f32_16x16x32_bf16(A2b[e], B1b, acc1, 0, 0, 0);
      acc0 = __builtin_amdgcn_mfma_f32_16x16x32_bf16(A1a[e], B3a, acc0, 0, 0, 0);
      acc1 = __builtin_amdgcn_mfma_f32_16x16x32_bf16(A1b[e], B3b, acc1, 0, 0, 0);
      acc0 = __builtin_amdgcn_mfma_f32_16x16x32_bf16(A2a[e], B2a, acc0, 0, 0, 0);
      acc1 = __builtin_amdgcn_mfma_f32_16x16x32_bf16(A2b[e], B2b, acc1, 0, 0, 0);
      acc0 = __builtin_amdgcn_mfma_f32_16x16x32_bf16(A3a[e], B1a, acc0, 0, 0, 0);
      acc1 = __builtin_amdgcn_mfma_f32_16x16x32_bf16(A3b[e], B1b, acc1, 0, 0, 0);
      unsigned ck[4];
#pragma unroll
      for (int r = 0; r < 4; ++r) {
        float sm2 = acc0[r] + acc1[r];
        float dd = __builtin_fmaf(-2.f, sm2, x2c);  // x2r dropped: row-const
        ck[r] = (encf(dd) & 0xFFFFFF00u) | (unsigned)ct;
      }
      if (ct == selftile + e) {  // wave-uniform: self col only in this tile
#pragma unroll
        for (int r = 0; r < 4; ++r)
          if (c == q * 4 + r) ck[r] = 0xFFFFFFFFu;
      }
#pragma unroll
      for (int r = 0; r < 4; ++r) {
        unsigned x = ck[r];
#pragma unroll
        for (int p = KNN - 1; p >= 1; --p)
          best[e][r][p] = umed3(best[e][r][p - 1], best[e][r][p], x);
        best[e][r][0] = min(best[e][r][0], x);
      }
    }
  }
  // ---- parallel exact in-place merge, one 16-row pass per row-set ----
#pragma unroll
  for (int pass = 0; pass < NSET; ++pass) {
    // write per-lane sorted lists: row lrow = q*4+r, list = wv*16+c
#pragma unroll
    for (int r = 0; r < 4; ++r) {
      int lrow = q * 4 + r;
      unsigned* dst = lm + lrow * 577 + (wv * 16 + c) * 9;
#pragma unroll
      for (int p = 0; p < KNN; ++p) dst[p] = best[pass][r][p];
    }
    __syncthreads();
    // level A: 16 rows x 16 mergers, 4 lists each (u64-lift, col-in-tile);
    // result written in place over the consumed region (exclusive ownership).
    {
      int arow = t >> 4, am = t & 15;
      unsigned* base = lm + arow * 577;
      const unsigned* l0 = base + (am * 4) * 9;
      u64 fin[KNN];
#pragma unroll
      for (int p = 0; p < KNN; ++p)
        fin[p] = (((u64)l0[p]) << 4) | (unsigned)((am * 4) & 15);
      for (int d = 1; d < 4; ++d) {
        const unsigned* ld = base + (am * 4 + d) * 9;
        unsigned cb = (unsigned)((am * 4 + d) & 15);
        for (int p = 0; p < KNN; ++p) {
          u64 ckk = (((u64)ld[p]) << 4) | cb;
          if (ckk >= fin[KNN - 1]) break;  // ld sorted ascending
#pragma unroll
          for (int p2 = 0; p2 < KNN; ++p2) {
            u64 ob = fin[p2];
            bool ex = ob < ckk;
            fin[p2] = ex ? ob : ckk;
            ckk = ex ? ckk : ob;
          }
        }
      }
      unsigned* dst = base + am * 36;  // lo/hi u32 pairs (577 is odd)
#pragma unroll
      for (int p = 0; p < KNN; ++p) {
        dst[2 * p] = (unsigned)fin[p];
        dst[2 * p + 1] = (unsigned)(fin[p] >> 32);
      }
    }
    __syncthreads();
    // level B: 16 rows x 4 mergers, 4 level-A results each, in place
    if (t < 64) {
      int brow = t >> 2, bm = t & 3;
      unsigned* base = lm + brow * 577;
      u64 fin[KNN];
      {
        const unsigned* s0 = base + (bm * 4) * 36;
#pragma unroll
        for (int p = 0; p < KNN; ++p)
          fin[p] = (((u64)s0[2 * p + 1]) << 32) | s0[2 * p];
      }
      for (int d = 1; d < 4; ++d) {
        const unsigned* sd = base + (bm * 4 + d) * 36;
        for (int p = 0; p < KNN; ++p) {
          u64 ckk = (((u64)sd[2 * p + 1]) << 32) | sd[2 * p];
          if (ckk >= fin[KNN - 1]) break;
#pragma unroll
          for (int p2 = 0; p2 < KNN; ++p2) {
            u64 ob = fin[p2];
            bool ex = ob < ckk;
            fin[p2] = ex ? ob : ckk;
            ckk = ex ? ckk : ob;
          }
        }
      }
      unsigned* dst = base + bm * 144;
#pragma unroll
      for (int p = 0; p < KNN; ++p) {
        dst[2 * p] = (unsigned)fin[p];
        dst[2 * p + 1] = (unsigned)(fin[p] >> 32);
      }
    }
    __syncthreads();
    // level C: 16 rows, final 4-list merge + decode + emit
    if (t < 16) {
      unsigned* base = lm + t * 577;
      u64 fin[KNN];
#pragma unroll
      for (int p = 0; p < KNN; ++p)
        fin[p] = (((u64)base[2 * p + 1]) << 32) | base[2 * p];
      for (int d = 1; d < 4; ++d) {
        const unsigned* sd = base + d * 144;
        for (int p = 0; p < KNN; ++p) {
          u64 ckk = (((u64)sd[2 * p + 1]) << 32) | sd[2 * p];
          if (ckk >= fin[KNN - 1]) break;
#pragma unroll
          for (int p2 = 0; p2 < KNN; ++p2) {
            u64 ob = fin[p2];
            bool ex = ob < ckk;
            fin[p2] = ex ? ob : ckk;
            ckk = ex ? ckk : ob;
          }
        }
      }
      int row = rb + pass * 16 + t;
      int* ob = g_nbr + ((size_t)b * n + row) * KNN;
#pragma unroll
      for (int p = 0; p < KNN; ++p) {
        int j = (int)((fin[p] >> 4) & 255u) * 16 + (int)(fin[p] & 15u);
        ob[p] = j & (n - 1);
      }
    }
    if (pass + 1 < NSET) __syncthreads();
  }
}

// ---------------- per-node u/v for EdgeConv layer-1 factorization ------------
__global__ __launch_bounds__(256) void uv_kernel(int level,
                                                 const float* __restrict__ w1g,
                                                 const float* __restrict__ b1g) {
  __shared__ float sw1[128 * 96];  // 48 KB
  __shared__ float sb1[96];
  int t = threadIdx.x;
  for (int q = t; q < 128 * 96; q += 256) sw1[q] = w1g[q];
  if (t < 96) sb1[t] = b1g[t];
  __syncthreads();
  const int n = level ? N2 : N1;
  const float* h = level ? g_h2 : g_h1;
  int b = blockIdx.x & 7;
  int nl = (blockIdx.x >> 3) * 64 + (t & 63);
  int c0 = (t >> 6) * 24;  // wave-uniform chunk
  size_t node = (size_t)b * n + nl;
  const float4* h4 = (const float4*)(h + node * HID);
  float hv[HID];
#pragma unroll
  for (int q = 0; q < 16; ++q) {
    float4 vv = h4[q];
    hv[4 * q] = vv.x; hv[4 * q + 1] = vv.y; hv[4 * q + 2] = vv.z; hv[4 * q + 3] = vv.w;
  }
  float ua[24], va[24];
#pragma unroll
  for (int c = 0; c < 24; ++c) { ua[c] = 0.f; va[c] = 0.f; }
  for (int d = 0; d < HID; ++d) {
    float hd = hv[d];
    const float* wt = sw1 + d * 96 + c0;        // wave-uniform -> broadcast
    const float* wb = sw1 + (HID + d) * 96 + c0;
#pragma unroll
    for (int c = 0; c < 24; ++c) {
      ua[c] += hd * wt[c];
      va[c] += hd * wb[c];
    }
  }
  float* ur = g_uu + node * 96 + c0;
  float* vr = g_vv + node * 96 + c0;
#pragma unroll
  for (int c = 0; c < 24; ++c) {
    float uval = ua[c] - va[c] + sb1[c0 + c];
    float vval = va[c];
    ur[c] = uval;
    vr[c] = vval;
    int kk = c0 + c;
    size_t fa = (node >> 4) * 1536 + (size_t)((kk >> 5) * 512 +
                ((kk >> 3) & 3) * 128 + (nl & 15) * 8 + (kk & 7));
    g_uf[fa] = uval;
    g_vf[fa] = vval;
  }
}

// ---------------- MFMA edge messages + max scatter (r17 config) --------------
// Wave = 16 nodes (one frag tile), 4 waves/block: W-frags hoisted once per
// 64 nodes and intra-block wave overlap hides the neighbor-gather latency.
// (r20's 1-wave split re-loaded W-frags 4x and regressed ~100us.)
template <int LEVEL>
__global__ __launch_bounds__(256, 1) void edge_kernel(
    const float* __restrict__ b2g) {
  constexpr int n = LEVEL ? N2 : N1;
  unsigned* ekey = LEVEL ? g_ek2 : g_ek1;
  int b = blockIdx.x & 7;  // XCD swizzle
  int t = threadIdx.x;
  int wv = t >> 6, lane = t & 63;
  int q = lane >> 4, c = lane & 15;
  int base16 = (blockIdx.x >> 3) * 64 + wv * 16;
  int node_c = base16 + c;
  const int* nbb = g_nbr + (size_t)b * n * KNN;
  const float* ub = g_uu + (size_t)b * n * 96;
  const float* vb = g_vv + (size_t)b * n * 96;
  size_t ftile = ((size_t)(b * n + base16) >> 4) * 1536;
  unsigned* eb = ekey + (size_t)b * n * HID;
  short8 W1f[4][3], W2f[4][3];
#pragma unroll
  for (int no = 0; no < 4; ++no)
#pragma unroll
    for (int kc = 0; kc < 3; ++kc) {
      int off = LEVEL * 6144 + ((no * 3 + kc) * 64 + lane) * 8;
      W1f[no][kc] = *(const short8*)(g_wf1 + off);
      W2f[no][kc] = *(const short8*)(g_wf2 + off);
    }
  float biasv[4];
#pragma unroll
  for (int no = 0; no < 4; ++no) biasv[no] = b2g[no * 16 + c];
  float macc[16];
#pragma unroll
  for (int e = 0; e < 16; ++e) macc[e] = -1.0f;
  for (int slot = 0; slot < KNN; ++slot) {
    int jn = nbb[(size_t)node_c * KNN + slot] & (n - 1);
    short8 t1[3], t2[3], r1[3], r2[3];
#pragma unroll
    for (int kc = 0; kc < 3; ++kc) {
      size_t fo = ftile + kc * 512 + lane * 8;
      float4 su0 = *(const float4*)(g_uf + fo);
      float4 su1 = *(const float4*)(g_uf + fo + 4);
      float4 sv0 = *(const float4*)(g_vf + fo);
      float4 sv1 = *(const float4*)(g_vf + fo + 4);
      size_t go = (size_t)jn * 96 + kc * 32 + q * 8;
      float4 gv0 = *(const float4*)(vb + go);
      float4 gv1 = *(const float4*)(vb + go + 4);
      float4 gu0 = *(const float4*)(ub + go);
      float4 gu1 = *(const float4*)(ub + go + 4);
      tv_frag(su0, su1, gv0, gv1, t1[kc], t2[kc]);   // fwd: u_i + v_j
      tv_frag(gu0, gu1, sv0, sv1, r1[kc], r2[kc]);   // rev: u_j + v_i
    }
    f32x4 aF[4], aR[4];
#pragma unroll
    for (int no = 0; no < 4; ++no) {
      aF[no] = (f32x4){0.f, 0.f, 0.f, 0.f};
      aR[no] = (f32x4){0.f, 0.f, 0.f, 0.f};
    }
#pragma unroll
    for (int no = 0; no < 4; ++no)
#pragma unroll
      for (int kc = 0; kc < 3; ++kc) {
        aF[no] = __builtin_amdgcn_mfma_f32_16x16x32_bf16(t1[kc], W1f[no][kc], aF[no], 0, 0, 0);
        aF[no] = __builtin_amdgcn_mfma_f32_16x16x32_bf16(t2[kc], W1f[no][kc], aF[no], 0, 0, 0);
        aF[no] = __builtin_amdgcn_mfma_f32_16x16x32_bf16(t1[kc], W2f[no][kc], aF[no], 0, 0, 0);
        aR[no] = __builtin_amdgcn_mfma_f32_16x16x32_bf16(r1[kc], W1f[no][kc], aR[no], 0, 0, 0);
        aR[no] = __builtin_amdgcn_mfma_f32_16x16x32_bf16(r2[kc], W1f[no][kc], aR[no], 0, 0, 0);
        aR[no] = __builtin_amdgcn_mfma_f32_16x16x32_bf16(r1[kc], W2f[no][kc], aR[no], 0, 0, 0);
      }
#pragma unroll
    for (int r = 0; r < 4; ++r) {
      int jr = nbb[(size_t)(base16 + q * 4 + r) * KNN + slot] & (n - 1);
#pragma unroll
      for (int no = 0; no < 4; ++no) {
        float mv = eluf(aR[no][r] + biasv[no]);
        atomicMax(&eb[(size_t)jr * HID + no * 16 + c], enc_safe(mv));
      }
    }
#pragma unroll
    for (int no = 0; no < 4; ++no)
#pragma unroll
      for (int r = 0; r < 4; ++r)
        macc[no * 4 + r] = fmaxf(macc[no * 4 + r], eluf(aF[no][r] + biasv[no]));
  }
#pragma unroll
  for (int r = 0; r < 4; ++r) {
    size_t ib = (size_t)(base16 + q * 4 + r) * HID;
#pragma unroll
    for (int no = 0; no < 4; ++no)
      atomicMax(&eb[ib + no * 16 + c], enc_safe(macc[no * 4 + r]));
  }
}

// ---------------- pairwise max pool + norms + bf16 splits --------------------
__global__ __launch_bounds__(256) void pool_kernel() {
  int node = blockIdx.x * 256 + threadIdx.x;  // < BATCH*N2
  int b = node >> 11;
  int m = node & (N2 - 1);
  const unsigned* e = g_ek1 + ((size_t)b * N1 + 2 * m) * HID;
  float* hr = g_h2 + (size_t)node * HID;
  float sq = 0.f;
  short s1l[HID], s2l[HID], s3l[HID];
#pragma unroll
  for (int d = 0; d < HID; ++d) {
    float mx = fmaxf(dec_safe(e[d]), dec_safe(e[HID + d]));
    hr[d] = mx;
    sq += mx * mx;
    split3(mx, s1l[d], s2l[d], s3l[d]);
  }
  store_frags(node, s1l, s2l, s3l);
  g_x2n2[node] = sq;
}

// ---------------- global max + output MLP -> FLOAT32 output ------------------
// 256 threads: 4-way row-split scan of g_ek2 + LDS combine.
__global__ __launch_bounds__(256) void final_kernel(
    const float* __restrict__ wo1, const float* __restrict__ bo1,
    const float* __restrict__ wo2, const float* __restrict__ bo2,
    const float* __restrict__ wo3, const float* __restrict__ bo3,
    float* __restrict__ out) {
  __shared__ unsigned red[4][HID];
  __shared__ float g[HID];
  __shared__ float o1s[HID];
  __shared__ float o2s[32];
  int b = blockIdx.x;
  int t = threadIdx.x;  // 0..255
  int grp = t >> 6, d = t & 63;
  const unsigned* e = g_ek2 + (size_t)b * N2 * HID;
  unsigned mk = 0u;
  for (int m = grp; m < N2; m += 4) {
    unsigned qv = e[(size_t)m * HID + d];
    mk = qv > mk ? qv : mk;
  }
  red[grp][d] = mk;
  __syncthreads();
  if (t < HID) {
    unsigned q1 = red[0][t] > red[1][t] ? red[0][t] : red[1][t];
    unsigned q2 = red[2][t] > red[3][t] ? red[2][t] : red[3][t];
    g[t] = dec_safe(q1 > q2 ? q1 : q2);
  }
  __syncthreads();
  if (t < HID) {
    float a1 = bo1[t];
    for (int dd = 0; dd < HID; ++dd) a1 += g[dd] * wo1[dd * HID + t];
    o1s[t] = eluf(a1);
  }
  __syncthreads();
  if (t < 32) {
    float a2 = bo2[t];
    for (int dd = 0; dd < HID; ++dd) a2 += o1s[dd] * wo2[dd * 32 + t];
    o2s[t] = eluf(a2);
  }
  __syncthreads();
  if (t == 0) {
    float acc0 = bo3[0];
    float acc1 = bo3[1];
    for (int dd = 0; dd < 32; ++dd) {
      acc0 += o2s[dd] * wo3[dd * 2 + 0];
      acc1 += o2s[dd] * wo3[dd * 2 + 1];
    }
    float met = fmaxf(acc0, 0.f) + log1pf(expf(-fabsf(acc0)));      // softplus
    float phi = 3.14159265358979f * (2.f / (1.f + expf(-acc1)) - 1.f);
    out[b * 2 + 0] = met;
    out[b * 2 + 1] = phi;
  }
}

extern "C" void kernel_launch(void* const* d_in, const int* in_sizes, int n_in,
                              void* d_out, int out_size, void* d_ws,
                              size_t ws_size, hipStream_t stream) {
  const float* x     = (const float*)d_in[0];
  const float* dnorm = (const float*)d_in[1];
  const float* w_in1 = (const float*)d_in[2];
  const float* b_in1 = (const float*)d_in[3];
  const float* w_in2 = (const float*)d_in[4];
  const float* b_in2 = (const float*)d_in[5];
  const float* w_c1a = (const float*)d_in[6];
  const float* b_c1a = (const float*)d_in[7];
  const float* w_c1b = (const float*)d_in[8];
  const float* b_c1b = (const float*)d_in[9];
  const float* w_c2a = (const float*)d_in[10];
  const float* b_c2a = (const float*)d_in[11];
  const float* w_c2b = (const float*)d_in[12];
  const float* b_c2b = (const float*)d_in[13];
  const float* w_o1  = (const float*)d_in[14];
  const float* b_o1  = (const float*)d_in[15];
  const float* w_o2  = (const float*)d_in[16];
  const float* b_o2  = (const float*)d_in[17];
  const float* w_o3  = (const float*)d_in[18];
  const float* b_o3  = (const float*)d_in[19];

  init_kernel<<<(BATCH * N1 * HID + BATCH * N2 * HID) / 4 / 256, 256, 0,
                stream>>>();
  wfrag_kernel<<<2, 256, 0, stream>>>(w_c1b, w_c2b);
  input_mlp<<<BATCH * N1 / 256, 256, 0, stream>>>(x, dnorm, w_in1, b_in1,
                                                  w_in2, b_in2);
  knn_kernel<0><<<8 * (N1 / 32), 256, 0, stream>>>();   // 32 rows/block
  uv_kernel<<<8 * (N1 / 64), 256, 0, stream>>>(0, w_c1a, b_c1a);
  edge_kernel<0><<<8 * (N1 / 64), 256, 0, stream>>>(b_c1b);
  pool_kernel<<<BATCH * N2 / 256, 256, 0, stream>>>();
  knn_kernel<1><<<8 * (N2 / 16), 256, 0, stream>>>();   // 16 rows/block
  uv_kernel<<<8 * (N2 / 64), 256, 0, stream>>>(1, w_c2a, b_c2a);
  edge_kernel<1><<<8 * (N2 / 64), 256, 0, stream>>>(b_c2b);
  final_kernel<<<BATCH, 256, 0, stream>>>(w_o1, b_o1, w_o2, b_o2, w_o3, b_o3,
                                          (float*)d_out);
}

// Round 7
// 605.058 us; speedup vs baseline: 1.0138x; 1.0138x over previous
//
#include <hip/hip_runtime.h>
#include <hip/hip_bf16.h>

#define BATCH 8
#define N1 4096
#define N2 2048
#define HID 64
#define KNN 8
#define INDIM 10

using u64 = unsigned long long;
using bf16 = __hip_bfloat16;
typedef __attribute__((ext_vector_type(8))) short short8;
typedef __attribute__((ext_vector_type(4))) float f32x4;

// Scratch in static device memory (~115 MB): d_ws size is not guaranteed.
// Every buffer is fully rewritten each call (or re-initialized by init_kernel).
__device__ __align__(256) float    g_h1[BATCH * N1 * HID];
__device__ __align__(256) float    g_h2[BATCH * N2 * HID];
__device__ __align__(256) float    g_x2n[BATCH * N1];
__device__ __align__(256) float    g_x2n2[BATCH * N2];
__device__ __align__(256) int      g_nbr[BATCH * N1 * KNN];
__device__ __align__(256) float    g_uu[BATCH * N1 * 96];
__device__ __align__(256) float    g_vv[BATCH * N1 * 96];
__device__ __align__(256) unsigned g_ek1[BATCH * N1 * HID];
__device__ __align__(256) unsigned g_ek2[BATCH * N2 * HID];
// 3-way bf16 split of h in MFMA FRAGMENT-MAJOR layout (kNN):
// [tile16][chunk(2)][q(4)][c(16)][j(8)] shorts; node i=tile*16+c.
__device__ __align__(256) short    g_f1[BATCH * N1 * HID];
__device__ __align__(256) short    g_f2[BATCH * N1 * HID];
__device__ __align__(256) short    g_f3[BATCH * N1 * HID];
// frag-major f32 copies of u,v for edge MFMA A-prep:
// [tile16][kc(3)][q(4)][c(16)][j(8)] floats, node = tile*16+c, kk=kc*32+q*8+j.
__device__ __align__(256) float    g_uf[BATCH * N1 * 96];
__device__ __align__(256) float    g_vf[BATCH * N1 * 96];
// 2-way bf16 split W2 fragments: [level][no(4)][kc(3)][lane(64)][j(8)]
__device__ __align__(256) short    g_wf1[2 * 4 * 3 * 64 * 8];
__device__ __align__(256) short    g_wf2[2 * 4 * 3 * 64 * 8];

__device__ __forceinline__ float eluf(float x) { return x > 0.f ? x : __expf(x) - 1.f; }
// order-isomorphic float->u32 encoding: a<b  <=>  enc(a)<enc(b) (unsigned)
__device__ __forceinline__ unsigned encf(float f) {
  unsigned u = __float_as_uint(f);
  return u ^ ((unsigned)((int)u >> 31) | 0x80000000u);
}
__device__ __forceinline__ float decf(unsigned k) {
  unsigned u = (k & 0x80000000u) ? (k & 0x7FFFFFFFu) : ~k;
  return __uint_as_float(u);
}
// encf(-1.0f): ELU outputs are strictly > -1 => legal max-identity.
#define ENC_NEG1 0x407FFFFFu
__device__ __forceinline__ unsigned enc_safe(float v) {
  if (!(v == v)) return ENC_NEG1;
  return encf(v);
}
__device__ __forceinline__ float dec_safe(unsigned k) {
  float v = decf(k);
  if (!(v == v)) return -1.0f;
  return fminf(fmaxf(v, -3.0e38f), 3.0e38f);
}
// v_med3_u32: median of three u32. Inserting x into a SORTED ascending list a:
// r[i] = med3(a[i-1], a[i], x)  (r[0] = min(a[0], x)) -- 8 independent ops,
// half the op count of the min/max bubble and no serial dep chain.
__device__ __forceinline__ unsigned umed3(unsigned a, unsigned b, unsigned c) {
  unsigned d;
  asm("v_med3_u32 %0, %1, %2, %3" : "=v"(d) : "v"(a), "v"(b), "v"(c));
  return d;
}
// 3-way bf16 split: v ~= b1 + b2 + b3 (error ~2^-25 relative)
__device__ __forceinline__ void split3(float v, short& b1, short& b2, short& b3) {
  bf16 x1 = __float2bfloat16(v);
  float r1 = v - __bfloat162float(x1);
  bf16 x2 = __float2bfloat16(r1);
  float r2 = r1 - __bfloat162float(x2);
  bf16 x3 = __float2bfloat16(r2);
  b1 = *(short*)&x1; b2 = *(short*)&x2; b3 = *(short*)&x3;
}
// 2-way bf16 split
__device__ __forceinline__ void split2(float v, short& b1, short& b2) {
  bf16 x1 = __float2bfloat16(v);
  float r1 = v - __bfloat162float(x1);
  bf16 x2 = __float2bfloat16(r1);
  b1 = *(short*)&x1; b2 = *(short*)&x2;
}
// write one node's 64 splits into kNN fragment-major layout
__device__ __forceinline__ void store_frags(int node, const short* s1,
                                            const short* s2, const short* s3) {
  size_t tb = ((size_t)(node >> 4)) * 1024 + (node & 15) * 8;
#pragma unroll
  for (int chunk = 0; chunk < 2; ++chunk) {
#pragma unroll
    for (int q = 0; q < 4; ++q) {
      size_t a = tb + chunk * 512 + q * 128;
      int k = chunk * 32 + q * 8;
      *(short8*)(g_f1 + a) = *(const short8*)(s1 + k);
      *(short8*)(g_f2 + a) = *(const short8*)(s2 + k);
      *(short8*)(g_f3 + a) = *(const short8*)(s3 + k);
    }
  }
}
// elu(a+b) for 8 floats -> 2-way split short8 frags
__device__ __forceinline__ void tv_frag(float4 a0, float4 a1, float4 b0,
                                        float4 b1, short8& s1, short8& s2) {
  float v[8] = {a0.x + b0.x, a0.y + b0.y, a0.z + b0.z, a0.w + b0.w,
                a1.x + b1.x, a1.y + b1.y, a1.z + b1.z, a1.w + b1.w};
#pragma unroll
  for (int e = 0; e < 8; ++e) {
    float t = eluf(v[e]);
    short p1, p2;
    split2(t, p1, p2);
    s1[e] = p1; s2[e] = p2;
  }
}

// ---------------- init the scatter-max accumulators --------------------------
__global__ __launch_bounds__(256) void init_kernel() {
  int t = blockIdx.x * 256 + threadIdx.x;
  uint4 z = make_uint4(ENC_NEG1, ENC_NEG1, ENC_NEG1, ENC_NEG1);
  const int n1 = BATCH * N1 * HID / 4;
  if (t < n1) ((uint4*)g_ek1)[t] = z;
  else ((uint4*)g_ek2)[t - n1] = z;
}

// ---------------- W2 -> 2-way-split MFMA B-fragments (once per launch) -------
__global__ __launch_bounds__(256) void wfrag_kernel(const float* __restrict__ w1,
                                                    const float* __restrict__ w2) {
  int level = blockIdx.x;
  const float* w = level ? w2 : w1;
  for (int idx = threadIdx.x; idx < 6144; idx += 256) {
    int no = idx / 1536;
    int rem = idx - no * 1536;
    int kc = rem / 512;
    int rem2 = rem - kc * 512;
    int lane = rem2 >> 3;
    int j = rem2 & 7;
    int k = kc * 32 + (lane >> 4) * 8 + j;
    int o = no * 16 + (lane & 15);
    short b1, b2;
    split2(w[k * 64 + o], b1, b2);
    g_wf1[level * 6144 + idx] = b1;
    g_wf2[level * 6144 + idx] = b2;
  }
}

// ---------------- input MLP: x*norm -> 32 (elu) -> 64 (elu) + |h|^2 + splits -
__global__ __launch_bounds__(256) void input_mlp(
    const float* __restrict__ x, const float* __restrict__ norm,
    const float* __restrict__ w1g, const float* __restrict__ b1g,
    const float* __restrict__ w2g, const float* __restrict__ b2g) {
  __shared__ float sw1[320], sb1[32], sw2[2048], sb2[64], snorm[INDIM];
  int t = threadIdx.x;
  for (int q = t; q < 320; q += 256) sw1[q] = w1g[q];
  for (int q = t; q < 2048; q += 256) sw2[q] = w2g[q];
  if (t < 32) sb1[t] = b1g[t];
  if (t < 64) sb2[t] = b2g[t];
  if (t < INDIM) snorm[t] = norm[t];
  __syncthreads();
  int node = blockIdx.x * 256 + t;  // < BATCH*N1
  float xv[INDIM];
#pragma unroll
  for (int d = 0; d < INDIM; ++d)
    xv[d] = x[(size_t)node * INDIM + d] * snorm[d];
  float t1[32];
#pragma unroll
  for (int c = 0; c < 32; ++c) {
    float acc = sb1[c];
#pragma unroll
    for (int d = 0; d < INDIM; ++d) acc += xv[d] * sw1[d * 32 + c];
    t1[c] = eluf(acc);
  }
  float* hr = g_h1 + (size_t)node * HID;
  float sq = 0.f;
  short s1l[HID], s2l[HID], s3l[HID];
#pragma unroll
  for (int c = 0; c < HID; ++c) {
    float acc = sb2[c];
#pragma unroll
    for (int d = 0; d < 32; ++d) acc += t1[d] * sw2[d * HID + c];
    float v = eluf(acc);
    hr[c] = v;
    sq += v * v;
    split3(v, s1l[c], s2l[c], s3l[c]);
  }
  store_frags(node, s1l, s2l, s3l);
  g_x2n[node] = sq;
}

// ---------------- MFMA Gram-matrix kNN (k=8), u32-key med3 selection ---------
// r27: r26 structure, launch_bounds(256) with NO waves-per-EU arg.
// Cross-round occupancy table (r21-r26) shows measured blocks/CU ==
// launch_bounds arg2 in every configuration, even when grid/LDS/VGPR all
// permit more (r26: grid 4, LDS 4, VGPR-class 4, measured 2). Empirically
// the arg acts as an occupancy CAP on this toolchain (and at (256,4) also
// caps the allocator at 64 VGPR -> r23 spill). Dropping the arg removes
// both caps: compiler stays ~84 VGPR (no pressure), scheduler free to
// co-resident 4 blocks/CU (LDS 160/37.4). Geometry unchanged from r26:
// 256-thr block = one 32-row strip (NSET=2), 4 waves = column quarters,
// grid 8*(N1/32)=1024; total B L2 traffic 1.57 GB; in-place 3-level merge.
template <int LEVEL>
__global__ __launch_bounds__(256) void knn_kernel() {
  constexpr int n = LEVEL ? N2 : N1;
  constexpr int NT = n / 16;           // column tiles in batch
  constexpr int QT = NT / 4;           // tiles per column quarter
  constexpr int NSET = LEVEL ? 1 : 2;  // 16-row A-tiles per block
  constexpr int ROWS = NSET * 16;      // rows per block
  __shared__ unsigned lm[16 * 577];    // 36,928 B (one 16-row pass)

  int b = blockIdx.x & 7;              // XCD-friendly batch swizzle
  int rb = (blockIdx.x >> 3) * ROWS;
  int t = threadIdx.x;
  int wv = t >> 6, lane = t & 63;      // wv = column quarter
  int q = lane >> 4, c = lane & 15;
  const float* __restrict__ x2b = (LEVEL ? g_x2n2 : g_x2n) + (size_t)b * n;
  size_t abase = ((size_t)((b * n + rb) >> 4)) * 1024 + lane * 8;
  short8 A1a[NSET], A1b[NSET], A2a[NSET], A2b[NSET], A3a[NSET], A3b[NSET];
#pragma unroll
  for (int e = 0; e < NSET; ++e) {
    size_t ab = abase + (size_t)e * 1024;
    A1a[e] = *(const short8*)(g_f1 + ab);
    A1b[e] = *(const short8*)(g_f1 + ab + 512);
    A2a[e] = *(const short8*)(g_f2 + ab);
    A2b[e] = *(const short8*)(g_f2 + ab + 512);
    A3a[e] = *(const short8*)(g_f3 + ab);
    A3b[e] = *(const short8*)(g_f3 + ab + 512);
  }
  unsigned best[NSET][4][KNN];
#pragma unroll
  for (int e = 0; e < NSET; ++e)
#pragma unroll
    for (int r = 0; r < 4; ++r)
#pragma unroll
      for (int p = 0; p < KNN; ++p) best[e][r][p] = 0xFFFFFFFFu;
  const int ct0 = wv * QT;
  const int selftile = rb >> 4;        // + e = only tile with cb==i
  const f32x4 zero = {0.f, 0.f, 0.f, 0.f};
  size_t bb = ((size_t)(b * n) >> 4) * 1024 + (size_t)ct0 * 1024 + lane * 8;
  for (int ct = ct0; ct < ct0 + QT; ++ct, bb += 1024) {
    short8 B1a = *(const short8*)(g_f1 + bb);
    short8 B1b = *(const short8*)(g_f1 + bb + 512);
    short8 B2a = *(const short8*)(g_f2 + bb);
    short8 B2b = *(const short8*)(g_f2 + bb + 512);
    short8 B3a = *(const short8*)(g_f3 + bb);
    short8 B3b = *(const short8*)(g_f3 + bb + 512);
    float x2c = x2b[ct * 16 + c];
#pragma unroll
    for (int e = 0; e < NSET; ++e) {
      f32x4 acc0 = __builtin_amdgcn_mfma_f32_16x16x32_bf16(A1a[e], B1a, zero, 0, 0, 0);
      f32x4 acc1 = __builtin_amdgcn_mfma_f32_16x16x32_bf16(A1b[e], B1b, zero, 0, 0, 0);
      acc0 = __builtin_amdgcn_mfma_f32_16x16x32_bf16(A1a[e], B2a, acc0, 0, 0, 0);
      acc1 = __builtin_amdgcn_mfma_f32_16x16x32_bf16(A1b[e], B2b, acc1, 0, 0, 0);
      acc0 = __builtin_amdgcn_mfma_f32_16x16x32_bf16(A2a[e], B1a, acc0, 0, 0, 0);
      acc1 = __builtin_amdgcn_mfma_f32_16x16x32_bf16(A2b[e], B1b, acc1, 0, 0, 0);
      acc0 = __builtin_amdgcn_mfma_f32_16x16x32_bf16(A1a[e], B3a, acc0, 0, 0, 0);
      acc1 = __builtin_amdgcn_mfma_f32_16x16x32_bf16(A1b[e], B3b, acc1, 0, 0, 0);
      acc0 = __builtin_amdgcn_mfma_f32_16x16x32_bf16(A2a[e], B2a, acc0, 0, 0, 0);
      acc1 = __builtin_amdgcn_mfma_f32_16x16x32_bf16(A2b[e], B2b, acc1, 0, 0, 0);
      acc0 = __builtin_amdgcn_mfma_f32_16x16x32_bf16(A3a[e], B1a, acc0, 0, 0, 0);
      acc1 = __builtin_amdgcn_mfma_f32_16x16x32_bf16(A3b[e], B1b, acc1, 0, 0, 0);
      unsigned ck[4];
#pragma unroll
      for (int r = 0; r < 4; ++r) {
        float sm2 = acc0[r] + acc1[r];
        float dd = __builtin_fmaf(-2.f, sm2, x2c);  // x2r dropped: row-const
        ck[r] = (encf(dd) & 0xFFFFFF00u) | (unsigned)ct;
      }
      if (ct == selftile + e) {  // wave-uniform: self col only in this tile
#pragma unroll
        for (int r = 0; r < 4; ++r)
          if (c == q * 4 + r) ck[r] = 0xFFFFFFFFu;
      }
#pragma unroll
      for (int r = 0; r < 4; ++r) {
        unsigned x = ck[r];
#pragma unroll
        for (int p = KNN - 1; p >= 1; --p)
          best[e][r][p] = umed3(best[e][r][p - 1], best[e][r][p], x);
        best[e][r][0] = min(best[e][r][0], x);
      }
    }
  }
  // ---- parallel exact in-place merge, one 16-row pass per row-set ----
#pragma unroll
  for (int pass = 0; pass < NSET; ++pass) {
    // write per-lane sorted lists: row lrow = q*4+r, list = wv*16+c
#pragma unroll
    for (int r = 0; r < 4; ++r) {
      int lrow = q * 4 + r;
      unsigned* dst = lm + lrow * 577 + (wv * 16 + c) * 9;
#pragma unroll
      for (int p = 0; p < KNN; ++p) dst[p] = best[pass][r][p];
    }
    __syncthreads();
    // level A: 16 rows x 16 mergers, 4 lists each (u64-lift, col-in-tile);
    // result written in place over the consumed region (exclusive ownership).
    {
      int arow = t >> 4, am = t & 15;
      unsigned* base = lm + arow * 577;
      const unsigned* l0 = base + (am * 4) * 9;
      u64 fin[KNN];
#pragma unroll
      for (int p = 0; p < KNN; ++p)
        fin[p] = (((u64)l0[p]) << 4) | (unsigned)((am * 4) & 15);
      for (int d = 1; d < 4; ++d) {
        const unsigned* ld = base + (am * 4 + d) * 9;
        unsigned cb = (unsigned)((am * 4 + d) & 15);
        for (int p = 0; p < KNN; ++p) {
          u64 ckk = (((u64)ld[p]) << 4) | cb;
          if (ckk >= fin[KNN - 1]) break;  // ld sorted ascending
#pragma unroll
          for (int p2 = 0; p2 < KNN; ++p2) {
            u64 ob = fin[p2];
            bool ex = ob < ckk;
            fin[p2] = ex ? ob : ckk;
            ckk = ex ? ckk : ob;
          }
        }
      }
      unsigned* dst = base + am * 36;  // lo/hi u32 pairs (577 is odd)
#pragma unroll
      for (int p = 0; p < KNN; ++p) {
        dst[2 * p] = (unsigned)fin[p];
        dst[2 * p + 1] = (unsigned)(fin[p] >> 32);
      }
    }
    __syncthreads();
    // level B: 16 rows x 4 mergers, 4 level-A results each, in place
    if (t < 64) {
      int brow = t >> 2, bm = t & 3;
      unsigned* base = lm + brow * 577;
      u64 fin[KNN];
      {
        const unsigned* s0 = base + (bm * 4) * 36;
#pragma unroll
        for (int p = 0; p < KNN; ++p)
          fin[p] = (((u64)s0[2 * p + 1]) << 32) | s0[2 * p];
      }
      for (int d = 1; d < 4; ++d) {
        const unsigned* sd = base + (bm * 4 + d) * 36;
        for (int p = 0; p < KNN; ++p) {
          u64 ckk = (((u64)sd[2 * p + 1]) << 32) | sd[2 * p];
          if (ckk >= fin[KNN - 1]) break;
#pragma unroll
          for (int p2 = 0; p2 < KNN; ++p2) {
            u64 ob = fin[p2];
            bool ex = ob < ckk;
            fin[p2] = ex ? ob : ckk;
            ckk = ex ? ckk : ob;
          }
        }
      }
      unsigned* dst = base + bm * 144;
#pragma unroll
      for (int p = 0; p < KNN; ++p) {
        dst[2 * p] = (unsigned)fin[p];
        dst[2 * p + 1] = (unsigned)(fin[p] >> 32);
      }
    }
    __syncthreads();
    // level C: 16 rows, final 4-list merge + decode + emit
    if (t < 16) {
      unsigned* base = lm + t * 577;
      u64 fin[KNN];
#pragma unroll
      for (int p = 0; p < KNN; ++p)
        fin[p] = (((u64)base[2 * p + 1]) << 32) | base[2 * p];
      for (int d = 1; d < 4; ++d) {
        const unsigned* sd = base + d * 144;
        for (int p = 0; p < KNN; ++p) {
          u64 ckk = (((u64)sd[2 * p + 1]) << 32) | sd[2 * p];
          if (ckk >= fin[KNN - 1]) break;
#pragma unroll
          for (int p2 = 0; p2 < KNN; ++p2) {
            u64 ob = fin[p2];
            bool ex = ob < ckk;
            fin[p2] = ex ? ob : ckk;
            ckk = ex ? ckk : ob;
          }
        }
      }
      int row = rb + pass * 16 + t;
      int* ob = g_nbr + ((size_t)b * n + row) * KNN;
#pragma unroll
      for (int p = 0; p < KNN; ++p) {
        int j = (int)((fin[p] >> 4) & 255u) * 16 + (int)(fin[p] & 15u);
        ob[p] = j & (n - 1);
      }
    }
    if (pass + 1 < NSET) __syncthreads();
  }
}

// ---------------- per-node u/v for EdgeConv layer-1 factorization ------------
__global__ __launch_bounds__(256) void uv_kernel(int level,
                                                 const float* __restrict__ w1g,
                                                 const float* __restrict__ b1g) {
  __shared__ float sw1[128 * 96];  // 48 KB
  __shared__ float sb1[96];
  int t = threadIdx.x;
  for (int q = t; q < 128 * 96; q += 256) sw1[q] = w1g[q];
  if (t < 96) sb1[t] = b1g[t];
  __syncthreads();
  const int n = level ? N2 : N1;
  const float* h = level ? g_h2 : g_h1;
  int b = blockIdx.x & 7;
  int nl = (blockIdx.x >> 3) * 64 + (t & 63);
  int c0 = (t >> 6) * 24;  // wave-uniform chunk
  size_t node = (size_t)b * n + nl;
  const float4* h4 = (const float4*)(h + node * HID);
  float hv[HID];
#pragma unroll
  for (int q = 0; q < 16; ++q) {
    float4 vv = h4[q];
    hv[4 * q] = vv.x; hv[4 * q + 1] = vv.y; hv[4 * q + 2] = vv.z; hv[4 * q + 3] = vv.w;
  }
  float ua[24], va[24];
#pragma unroll
  for (int c = 0; c < 24; ++c) { ua[c] = 0.f; va[c] = 0.f; }
  for (int d = 0; d < HID; ++d) {
    float hd = hv[d];
    const float* wt = sw1 + d * 96 + c0;        // wave-uniform -> broadcast
    const float* wb = sw1 + (HID + d) * 96 + c0;
#pragma unroll
    for (int c = 0; c < 24; ++c) {
      ua[c] += hd * wt[c];
      va[c] += hd * wb[c];
    }
  }
  float* ur = g_uu + node * 96 + c0;
  float* vr = g_vv + node * 96 + c0;
#pragma unroll
  for (int c = 0; c < 24; ++c) {
    float uval = ua[c] - va[c] + sb1[c0 + c];
    float vval = va[c];
    ur[c] = uval;
    vr[c] = vval;
    int kk = c0 + c;
    size_t fa = (node >> 4) * 1536 + (size_t)((kk >> 5) * 512 +
                ((kk >> 3) & 3) * 128 + (nl & 15) * 8 + (kk & 7));
    g_uf[fa] = uval;
    g_vf[fa] = vval;
  }
}

// ---------------- MFMA edge messages + max scatter (r17 config) --------------
// Wave = 16 nodes (one frag tile), 4 waves/block: W-frags hoisted once per
// 64 nodes and intra-block wave overlap hides the neighbor-gather latency.
// (r20's 1-wave split re-loaded W-frags 4x and regressed ~100us.)
template <int LEVEL>
__global__ __launch_bounds__(256, 1) void edge_kernel(
    const float* __restrict__ b2g) {
  constexpr int n = LEVEL ? N2 : N1;
  unsigned* ekey = LEVEL ? g_ek2 : g_ek1;
  int b = blockIdx.x & 7;  // XCD swizzle
  int t = threadIdx.x;
  int wv = t >> 6, lane = t & 63;
  int q = lane >> 4, c = lane & 15;
  int base16 = (blockIdx.x >> 3) * 64 + wv * 16;
  int node_c = base16 + c;
  const int* nbb = g_nbr + (size_t)b * n * KNN;
  const float* ub = g_uu + (size_t)b * n * 96;
  const float* vb = g_vv + (size_t)b * n * 96;
  size_t ftile = ((size_t)(b * n + base16) >> 4) * 1536;
  unsigned* eb = ekey + (size_t)b * n * HID;
  short8 W1f[4][3], W2f[4][3];
#pragma unroll
  for (int no = 0; no < 4; ++no)
#pragma unroll
    for (int kc = 0; kc < 3; ++kc) {
      int off = LEVEL * 6144 + ((no * 3 + kc) * 64 + lane) * 8;
      W1f[no][kc] = *(const short8*)(g_wf1 + off);
      W2f[no][kc] = *(const short8*)(g_wf2 + off);
    }
  float biasv[4];
#pragma unroll
  for (int no = 0; no < 4; ++no) biasv[no] = b2g[no * 16 + c];
  float macc[16];
#pragma unroll
  for (int e = 0; e < 16; ++e) macc[e] = -1.0f;
  for (int slot = 0; slot < KNN; ++slot) {
    int jn = nbb[(size_t)node_c * KNN + slot] & (n - 1);
    short8 t1[3], t2[3], r1[3], r2[3];
#pragma unroll
    for (int kc = 0; kc < 3; ++kc) {
      size_t fo = ftile + kc * 512 + lane * 8;
      float4 su0 = *(const float4*)(g_uf + fo);
      float4 su1 = *(const float4*)(g_uf + fo + 4);
      float4 sv0 = *(const float4*)(g_vf + fo);
      float4 sv1 = *(const float4*)(g_vf + fo + 4);
      size_t go = (size_t)jn * 96 + kc * 32 + q * 8;
      float4 gv0 = *(const float4*)(vb + go);
      float4 gv1 = *(const float4*)(vb + go + 4);
      float4 gu0 = *(const float4*)(ub + go);
      float4 gu1 = *(const float4*)(ub + go + 4);
      tv_frag(su0, su1, gv0, gv1, t1[kc], t2[kc]);   // fwd: u_i + v_j
      tv_frag(gu0, gu1, sv0, sv1, r1[kc], r2[kc]);   // rev: u_j + v_i
    }
    f32x4 aF[4], aR[4];
#pragma unroll
    for (int no = 0; no < 4; ++no) {
      aF[no] = (f32x4){0.f, 0.f, 0.f, 0.f};
      aR[no] = (f32x4){0.f, 0.f, 0.f, 0.f};
    }
#pragma unroll
    for (int no = 0; no < 4; ++no)
#pragma unroll
      for (int kc = 0; kc < 3; ++kc) {
        aF[no] = __builtin_amdgcn_mfma_f32_16x16x32_bf16(t1[kc], W1f[no][kc], aF[no], 0, 0, 0);
        aF[no] = __builtin_amdgcn_mfma_f32_16x16x32_bf16(t2[kc], W1f[no][kc], aF[no], 0, 0, 0);
        aF[no] = __builtin_amdgcn_mfma_f32_16x16x32_bf16(t1[kc], W2f[no][kc], aF[no], 0, 0, 0);
        aR[no] = __builtin_amdgcn_mfma_f32_16x16x32_bf16(r1[kc], W1f[no][kc], aR[no], 0, 0, 0);
        aR[no] = __builtin_amdgcn_mfma_f32_16x16x32_bf16(r2[kc], W1f[no][kc], aR[no], 0, 0, 0);
        aR[no] = __builtin_amdgcn_mfma_f32_16x16x32_bf16(r1[kc], W2f[no][kc], aR[no], 0, 0, 0);
      }
#pragma unroll
    for (int r = 0; r < 4; ++r) {
      int jr = nbb[(size_t)(base16 + q * 4 + r) * KNN + slot] & (n - 1);
#pragma unroll
      for (int no = 0; no < 4; ++no) {
        float mv = eluf(aR[no][r] + biasv[no]);
        atomicMax(&eb[(size_t)jr * HID + no * 16 + c], enc_safe(mv));
      }
    }
#pragma unroll
    for (int no = 0; no < 4; ++no)
#pragma unroll
      for (int r = 0; r < 4; ++r)
        macc[no * 4 + r] = fmaxf(macc[no * 4 + r], eluf(aF[no][r] + biasv[no]));
  }
#pragma unroll
  for (int r = 0; r < 4; ++r) {
    size_t ib = (size_t)(base16 + q * 4 + r) * HID;
#pragma unroll
    for (int no = 0; no < 4; ++no)
      atomicMax(&eb[ib + no * 16 + c], enc_safe(macc[no * 4 + r]));
  }
}

// ---------------- pairwise max pool + norms + bf16 splits --------------------
__global__ __launch_bounds__(256) void pool_kernel() {
  int node = blockIdx.x * 256 + threadIdx.x;  // < BATCH*N2
  int b = node >> 11;
  int m = node & (N2 - 1);
  const unsigned* e = g_ek1 + ((size_t)b * N1 + 2 * m) * HID;
  float* hr = g_h2 + (size_t)node * HID;
  float sq = 0.f;
  short s1l[HID], s2l[HID], s3l[HID];
#pragma unroll
  for (int d = 0; d < HID; ++d) {
    float mx = fmaxf(dec_safe(e[d]), dec_safe(e[HID + d]));
    hr[d] = mx;
    sq += mx * mx;
    split3(mx, s1l[d], s2l[d], s3l[d]);
  }
  store_frags(node, s1l, s2l, s3l);
  g_x2n2[node] = sq;
}

// ---------------- global max + output MLP -> FLOAT32 output ------------------
// 256 threads: 4-way row-split scan of g_ek2 + LDS combine.
__global__ __launch_bounds__(256) void final_kernel(
    const float* __restrict__ wo1, const float* __restrict__ bo1,
    const float* __restrict__ wo2, const float* __restrict__ bo2,
    const float* __restrict__ wo3, const float* __restrict__ bo3,
    float* __restrict__ out) {
  __shared__ unsigned red[4][HID];
  __shared__ float g[HID];
  __shared__ float o1s[HID];
  __shared__ float o2s[32];
  int b = blockIdx.x;
  int t = threadIdx.x;  // 0..255
  int grp = t >> 6, d = t & 63;
  const unsigned* e = g_ek2 + (size_t)b * N2 * HID;
  unsigned mk = 0u;
  for (int m = grp; m < N2; m += 4) {
    unsigned qv = e[(size_t)m * HID + d];
    mk = qv > mk ? qv : mk;
  }
  red[grp][d] = mk;
  __syncthreads();
  if (t < HID) {
    unsigned q1 = red[0][t] > red[1][t] ? red[0][t] : red[1][t];
    unsigned q2 = red[2][t] > red[3][t] ? red[2][t] : red[3][t];
    g[t] = dec_safe(q1 > q2 ? q1 : q2);
  }
  __syncthreads();
  if (t < HID) {
    float a1 = bo1[t];
    for (int dd = 0; dd < HID; ++dd) a1 += g[dd] * wo1[dd * HID + t];
    o1s[t] = eluf(a1);
  }
  __syncthreads();
  if (t < 32) {
    float a2 = bo2[t];
    for (int dd = 0; dd < HID; ++dd) a2 += o1s[dd] * wo2[dd * 32 + t];
    o2s[t] = eluf(a2);
  }
  __syncthreads();
  if (t == 0) {
    float acc0 = bo3[0];
    float acc1 = bo3[1];
    for (int dd = 0; dd < 32; ++dd) {
      acc0 += o2s[dd] * wo3[dd * 2 + 0];
      acc1 += o2s[dd] * wo3[dd * 2 + 1];
    }
    float met = fmaxf(acc0, 0.f) + log1pf(expf(-fabsf(acc0)));      // softplus
    float phi = 3.14159265358979f * (2.f / (1.f + expf(-acc1)) - 1.f);
    out[b * 2 + 0] = met;
    out[b * 2 + 1] = phi;
  }
}

extern "C" void kernel_launch(void* const* d_in, const int* in_sizes, int n_in,
                              void* d_out, int out_size, void* d_ws,
                              size_t ws_size, hipStream_t stream) {
  const float* x     = (const float*)d_in[0];
  const float* dnorm = (const float*)d_in[1];
  const float* w_in1 = (const float*)d_in[2];
  const float* b_in1 = (const float*)d_in[3];
  const float* w_in2 = (const float*)d_in[4];
  const float* b_in2 = (const float*)d_in[5];
  const float* w_c1a = (const float*)d_in[6];
  const float* b_c1a = (const float*)d_in[7];
  const float* w_c1b = (const float*)d_in[8];
  const float* b_c1b = (const float*)d_in[9];
  const float* w_c2a = (const float*)d_in[10];
  const float* b_c2a = (const float*)d_in[11];
  const float* w_c2b = (const float*)d_in[12];
  const float* b_c2b = (const float*)d_in[13];
  const float* w_o1  = (const float*)d_in[14];
  const float* b_o1  = (const float*)d_in[15];
  const float* w_o2  = (const float*)d_in[16];
  const float* b_o2  = (const float*)d_in[17];
  const float* w_o3  = (const float*)d_in[18];
  const float* b_o3  = (const float*)d_in[19];

  init_kernel<<<(BATCH * N1 * HID + BATCH * N2 * HID) / 4 / 256, 256, 0,
                stream>>>();
  wfrag_kernel<<<2, 256, 0, stream>>>(w_c1b, w_c2b);
  input_mlp<<<BATCH * N1 / 256, 256, 0, stream>>>(x, dnorm, w_in1, b_in1,
                                                  w_in2, b_in2);
  knn_kernel<0><<<8 * (N1 / 32), 256, 0, stream>>>();   // 32 rows/block
  uv_kernel<<<8 * (N1 / 64), 256, 0, stream>>>(0, w_c1a, b_c1a);
  edge_kernel<0><<<8 * (N1 / 64), 256, 0, stream>>>(b_c1b);
  pool_kernel<<<BATCH * N2 / 256, 256, 0, stream>>>();
  knn_kernel<1><<<8 * (N2 / 16), 256, 0, stream>>>();   // 16 rows/block
  uv_kernel<<<8 * (N2 / 64), 256, 0, stream>>>(1, w_c2a, b_c2a);
  edge_kernel<1><<<8 * (N2 / 64), 256, 0, stream>>>(b_c2b);
  final_kernel<<<BATCH, 256, 0, stream>>>(w_o1, b_o1, w_o2, b_o2, w_o3, b_o3,
                                          (float*)d_out);
}

// Round 8
// 564.001 us; speedup vs baseline: 1.0876x; 1.0728x over previous
//
#include <hip/hip_runtime.h>
#include <hip/hip_bf16.h>

#define BATCH 8
#define N1 4096
#define N2 2048
#define HID 64
#define KNN 8
#define INDIM 10

using u64 = unsigned long long;
using bf16 = __hip_bfloat16;
typedef __attribute__((ext_vector_type(8))) short short8;
typedef __attribute__((ext_vector_type(4))) float f32x4;

// Scratch in static device memory (~115 MB): d_ws size is not guaranteed.
// Every buffer is fully rewritten each call (or re-initialized by init_kernel).
__device__ __align__(256) float    g_h1[BATCH * N1 * HID];
__device__ __align__(256) float    g_h2[BATCH * N2 * HID];
__device__ __align__(256) float    g_x2n[BATCH * N1];
__device__ __align__(256) float    g_x2n2[BATCH * N2];
__device__ __align__(256) int      g_nbr[BATCH * N1 * KNN];
__device__ __align__(256) float    g_uu[BATCH * N1 * 96];
__device__ __align__(256) float    g_vv[BATCH * N1 * 96];
__device__ __align__(256) unsigned g_ek1[BATCH * N1 * HID];
__device__ __align__(256) unsigned g_ek2[BATCH * N2 * HID];
// 3-way bf16 split of h in MFMA FRAGMENT-MAJOR layout (kNN):
// [tile16][chunk(2)][q(4)][c(16)][j(8)] shorts; node i=tile*16+c.
__device__ __align__(256) short    g_f1[BATCH * N1 * HID];
__device__ __align__(256) short    g_f2[BATCH * N1 * HID];
__device__ __align__(256) short    g_f3[BATCH * N1 * HID];
// frag-major f32 copies of u,v for edge MFMA A-prep:
// [tile16][kc(3)][q(4)][c(16)][j(8)] floats, node = tile*16+c, kk=kc*32+q*8+j.
__device__ __align__(256) float    g_uf[BATCH * N1 * 96];
__device__ __align__(256) float    g_vf[BATCH * N1 * 96];
// 2-way bf16 split W2 fragments: [level][no(4)][kc(3)][lane(64)][j(8)]
__device__ __align__(256) short    g_wf1[2 * 4 * 3 * 64 * 8];
__device__ __align__(256) short    g_wf2[2 * 4 * 3 * 64 * 8];

__device__ __forceinline__ float eluf(float x) { return x > 0.f ? x : __expf(x) - 1.f; }
// order-isomorphic float->u32 encoding: a<b  <=>  enc(a)<enc(b) (unsigned)
__device__ __forceinline__ unsigned encf(float f) {
  unsigned u = __float_as_uint(f);
  return u ^ ((unsigned)((int)u >> 31) | 0x80000000u);
}
__device__ __forceinline__ float decf(unsigned k) {
  unsigned u = (k & 0x80000000u) ? (k & 0x7FFFFFFFu) : ~k;
  return __uint_as_float(u);
}
// encf(-1.0f): ELU outputs are strictly > -1 => legal max-identity.
#define ENC_NEG1 0x407FFFFFu
__device__ __forceinline__ unsigned enc_safe(float v) {
  if (!(v == v)) return ENC_NEG1;
  return encf(v);
}
__device__ __forceinline__ float dec_safe(unsigned k) {
  float v = decf(k);
  if (!(v == v)) return -1.0f;
  return fminf(fmaxf(v, -3.0e38f), 3.0e38f);
}
// v_med3_u32: median of three u32. Inserting x into a SORTED ascending list a:
// r[i] = med3(a[i-1], a[i], x)  (r[0] = min(a[0], x)) -- 8 independent ops,
// half the op count of the min/max bubble and no serial dep chain.
__device__ __forceinline__ unsigned umed3(unsigned a, unsigned b, unsigned c) {
  unsigned d;
  asm("v_med3_u32 %0, %1, %2, %3" : "=v"(d) : "v"(a), "v"(b), "v"(c));
  return d;
}
// 3-way bf16 split: v ~= b1 + b2 + b3 (error ~2^-25 relative)
__device__ __forceinline__ void split3(float v, short& b1, short& b2, short& b3) {
  bf16 x1 = __float2bfloat16(v);
  float r1 = v - __bfloat162float(x1);
  bf16 x2 = __float2bfloat16(r1);
  float r2 = r1 - __bfloat162float(x2);
  bf16 x3 = __float2bfloat16(r2);
  b1 = *(short*)&x1; b2 = *(short*)&x2; b3 = *(short*)&x3;
}
// 2-way bf16 split
__device__ __forceinline__ void split2(float v, short& b1, short& b2) {
  bf16 x1 = __float2bfloat16(v);
  float r1 = v - __bfloat162float(x1);
  bf16 x2 = __float2bfloat16(r1);
  b1 = *(short*)&x1; b2 = *(short*)&x2;
}
// write one node's 64 splits into kNN fragment-major layout
__device__ __forceinline__ void store_frags(int node, const short* s1,
                                            const short* s2, const short* s3) {
  size_t tb = ((size_t)(node >> 4)) * 1024 + (node & 15) * 8;
#pragma unroll
  for (int chunk = 0; chunk < 2; ++chunk) {
#pragma unroll
    for (int q = 0; q < 4; ++q) {
      size_t a = tb + chunk * 512 + q * 128;
      int k = chunk * 32 + q * 8;
      *(short8*)(g_f1 + a) = *(const short8*)(s1 + k);
      *(short8*)(g_f2 + a) = *(const short8*)(s2 + k);
      *(short8*)(g_f3 + a) = *(const short8*)(s3 + k);
    }
  }
}
// elu(a+b) for 8 floats -> 2-way split short8 frags
__device__ __forceinline__ void tv_frag(float4 a0, float4 a1, float4 b0,
                                        float4 b1, short8& s1, short8& s2) {
  float v[8] = {a0.x + b0.x, a0.y + b0.y, a0.z + b0.z, a0.w + b0.w,
                a1.x + b1.x, a1.y + b1.y, a1.z + b1.z, a1.w + b1.w};
#pragma unroll
  for (int e = 0; e < 8; ++e) {
    float t = eluf(v[e]);
    short p1, p2;
    split2(t, p1, p2);
    s1[e] = p1; s2[e] = p2;
  }
}

// ---------------- init the scatter-max accumulators --------------------------
__global__ __launch_bounds__(256) void init_kernel() {
  int t = blockIdx.x * 256 + threadIdx.x;
  uint4 z = make_uint4(ENC_NEG1, ENC_NEG1, ENC_NEG1, ENC_NEG1);
  const int n1 = BATCH * N1 * HID / 4;
  if (t < n1) ((uint4*)g_ek1)[t] = z;
  else ((uint4*)g_ek2)[t - n1] = z;
}

// ---------------- W2 -> 2-way-split MFMA B-fragments (once per launch) -------
__global__ __launch_bounds__(256) void wfrag_kernel(const float* __restrict__ w1,
                                                    const float* __restrict__ w2) {
  int level = blockIdx.x;
  const float* w = level ? w2 : w1;
  for (int idx = threadIdx.x; idx < 6144; idx += 256) {
    int no = idx / 1536;
    int rem = idx - no * 1536;
    int kc = rem / 512;
    int rem2 = rem - kc * 512;
    int lane = rem2 >> 3;
    int j = rem2 & 7;
    int k = kc * 32 + (lane >> 4) * 8 + j;
    int o = no * 16 + (lane & 15);
    short b1, b2;
    split2(w[k * 64 + o], b1, b2);
    g_wf1[level * 6144 + idx] = b1;
    g_wf2[level * 6144 + idx] = b2;
  }
}

// ---------------- input MLP: x*norm -> 32 (elu) -> 64 (elu) + |h|^2 + splits -
__global__ __launch_bounds__(256) void input_mlp(
    const float* __restrict__ x, const float* __restrict__ norm,
    const float* __restrict__ w1g, const float* __restrict__ b1g,
    const float* __restrict__ w2g, const float* __restrict__ b2g) {
  __shared__ float sw1[320], sb1[32], sw2[2048], sb2[64], snorm[INDIM];
  int t = threadIdx.x;
  for (int q = t; q < 320; q += 256) sw1[q] = w1g[q];
  for (int q = t; q < 2048; q += 256) sw2[q] = w2g[q];
  if (t < 32) sb1[t] = b1g[t];
  if (t < 64) sb2[t] = b2g[t];
  if (t < INDIM) snorm[t] = norm[t];
  __syncthreads();
  int node = blockIdx.x * 256 + t;  // < BATCH*N1
  float xv[INDIM];
#pragma unroll
  for (int d = 0; d < INDIM; ++d)
    xv[d] = x[(size_t)node * INDIM + d] * snorm[d];
  float t1[32];
#pragma unroll
  for (int c = 0; c < 32; ++c) {
    float acc = sb1[c];
#pragma unroll
    for (int d = 0; d < INDIM; ++d) acc += xv[d] * sw1[d * 32 + c];
    t1[c] = eluf(acc);
  }
  float* hr = g_h1 + (size_t)node * HID;
  float sq = 0.f;
  short s1l[HID], s2l[HID], s3l[HID];
#pragma unroll
  for (int c = 0; c < HID; ++c) {
    float acc = sb2[c];
#pragma unroll
    for (int d = 0; d < 32; ++d) acc += t1[d] * sw2[d * HID + c];
    float v = eluf(acc);
    hr[c] = v;
    sq += v * v;
    split3(v, s1l[c], s2l[c], s3l[c]);
  }
  store_frags(node, s1l, s2l, s3l);
  g_x2n[node] = sq;
}

// ---------------- MFMA Gram-matrix kNN (k=8), u32-key med3 selection ---------
// r28: r24 geometry (fastest measured: 155us knn<0>) + explicit 1-tile-deep
// REGISTER DOUBLE-BUFFER prefetch. Occupancy post-mortem across r21-r27:
// occupancy tracks the VGPR bucket (56 -> 36.6%; 84-88 -> 19-25%) and is
// INSENSITIVE to grid (2 vs 4 blk/CU), LDS (37-74 KB), and launch_bounds
// arg2 (r27: no arg, VGPR 88, still 19%) -- the 32-row/wave shape is pinned
// at ~2 waves/SIMD. So instead of occupancy, close the ~27% latency stall
// with ILP: unroll tile loop by 2 (ping-pong Pa/Pb, no reg copies); each
// phase issues the NEXT tile's 6 B-frag loads + x2c before the current
// phase's ~230-cycle selection VALU, hiding the ~200-cycle L1/L2 latency.
// Last prefetch clamped to a harmless reload. Geometry: grid 8*(N/64),
// block 256 = 2 row-strips x 2 column halves, NSET=2 (32 rows/wave),
// lm[32*289] 37 KB in-place 3-level merge, launch_bounds(256,2) (r23:
// (256,4) caps allocator at 64 VGPR -> 21 MB scratch spill).
template <int LEVEL>
__global__ __launch_bounds__(256, 2) void knn_kernel() {
  constexpr int n = LEVEL ? N2 : N1;
  constexpr int NT = n / 16;           // column tiles in batch
  constexpr int HT = NT / 2;           // tiles per column half (even: 128/64)
  constexpr int NSET = LEVEL ? 1 : 2;  // 16-row A-tiles per strip
  constexpr int SS = NSET * 16;        // rows per strip
  // lm: u32[32 rows][32 lists x 9] row-stride 289 (odd -> <=2-way banks)
  __shared__ unsigned lm[32 * 289];    // 36,992 B

  int b = blockIdx.x & 7;              // XCD-friendly batch swizzle
  int rb = (blockIdx.x >> 3) * (2 * SS);
  int t = threadIdx.x;
  int wv = t >> 6, lane = t & 63;
  int s = wv >> 1, hf = wv & 1;        // row strip / column half
  int q = lane >> 4, c = lane & 15;
  const float* __restrict__ x2b = (LEVEL ? g_x2n2 : g_x2n) + (size_t)b * n;
  size_t abase = ((size_t)((b * n + rb + s * SS) >> 4)) * 1024 + lane * 8;
  short8 A1a[NSET], A1b[NSET], A2a[NSET], A2b[NSET], A3a[NSET], A3b[NSET];
#pragma unroll
  for (int e = 0; e < NSET; ++e) {
    size_t ab = abase + (size_t)e * 1024;
    A1a[e] = *(const short8*)(g_f1 + ab);
    A1b[e] = *(const short8*)(g_f1 + ab + 512);
    A2a[e] = *(const short8*)(g_f2 + ab);
    A2b[e] = *(const short8*)(g_f2 + ab + 512);
    A3a[e] = *(const short8*)(g_f3 + ab);
    A3b[e] = *(const short8*)(g_f3 + ab + 512);
  }
  unsigned best[NSET][4][KNN];
#pragma unroll
  for (int e = 0; e < NSET; ++e)
#pragma unroll
    for (int r = 0; r < 4; ++r)
#pragma unroll
      for (int p = 0; p < KNN; ++p) best[e][r][p] = 0xFFFFFFFFu;
  const int ct0 = hf * HT;
  const int selftile = (rb + s * SS) >> 4;  // + e = only tile with cb==i
  const f32x4 zero = {0.f, 0.f, 0.f, 0.f};
  size_t bb = ((size_t)(b * n) >> 4) * 1024 + (size_t)ct0 * 1024 + lane * 8;

  // ping-pong B-fragment buffers: P[0..5] = B1a,B1b,B2a,B2b,B3a,B3b
  short8 Pa[6], Pb[6];
  float xa, xb;
  auto LOADB = [&](short8* P, size_t addr) {
    P[0] = *(const short8*)(g_f1 + addr);
    P[1] = *(const short8*)(g_f1 + addr + 512);
    P[2] = *(const short8*)(g_f2 + addr);
    P[3] = *(const short8*)(g_f2 + addr + 512);
    P[4] = *(const short8*)(g_f3 + addr);
    P[5] = *(const short8*)(g_f3 + addr + 512);
  };
  auto COMPUTE = [&](const short8* P, float x2c, int ct) {
#pragma unroll
    for (int e = 0; e < NSET; ++e) {
      f32x4 acc0 = __builtin_amdgcn_mfma_f32_16x16x32_bf16(A1a[e], P[0], zero, 0, 0, 0);
      f32x4 acc1 = __builtin_amdgcn_mfma_f32_16x16x32_bf16(A1b[e], P[1], zero, 0, 0, 0);
      acc0 = __builtin_amdgcn_mfma_f32_16x16x32_bf16(A1a[e], P[2], acc0, 0, 0, 0);
      acc1 = __builtin_amdgcn_mfma_f32_16x16x32_bf16(A1b[e], P[3], acc1, 0, 0, 0);
      acc0 = __builtin_amdgcn_mfma_f32_16x16x32_bf16(A2a[e], P[0], acc0, 0, 0, 0);
      acc1 = __builtin_amdgcn_mfma_f32_16x16x32_bf16(A2b[e], P[1], acc1, 0, 0, 0);
      acc0 = __builtin_amdgcn_mfma_f32_16x16x32_bf16(A1a[e], P[4], acc0, 0, 0, 0);
      acc1 = __builtin_amdgcn_mfma_f32_16x16x32_bf16(A1b[e], P[5], acc1, 0, 0, 0);
      acc0 = __builtin_amdgcn_mfma_f32_16x16x32_bf16(A2a[e], P[2], acc0, 0, 0, 0);
      acc1 = __builtin_amdgcn_mfma_f32_16x16x32_bf16(A2b[e], P[3], acc1, 0, 0, 0);
      acc0 = __builtin_amdgcn_mfma_f32_16x16x32_bf16(A3a[e], P[0], acc0, 0, 0, 0);
      acc1 = __builtin_amdgcn_mfma_f32_16x16x32_bf16(A3b[e], P[1], acc1, 0, 0, 0);
      unsigned ck[4];
#pragma unroll
      for (int r = 0; r < 4; ++r) {
        float sm2 = acc0[r] + acc1[r];
        float dd = __builtin_fmaf(-2.f, sm2, x2c);  // x2r dropped: row-const
        ck[r] = (encf(dd) & 0xFFFFFF00u) | (unsigned)ct;
      }
      if (ct == selftile + e) {  // wave-uniform: self col only in this tile
#pragma unroll
        for (int r = 0; r < 4; ++r)
          if (c == q * 4 + r) ck[r] = 0xFFFFFFFFu;
      }
#pragma unroll
      for (int r = 0; r < 4; ++r) {
        unsigned x = ck[r];
#pragma unroll
        for (int p = KNN - 1; p >= 1; --p)
          best[e][r][p] = umed3(best[e][r][p - 1], best[e][r][p], x);
        best[e][r][0] = min(best[e][r][0], x);
      }
    }
  };

  LOADB(Pa, bb);
  xa = x2b[ct0 * 16 + c];
  for (int tt = 0; tt < HT; tt += 2) {
    int ct = ct0 + tt;
    // phase A: prefetch tile ct+1 into Pb, compute tile ct from Pa
    LOADB(Pb, bb + 1024);
    xb = x2b[(ct + 1) * 16 + c];
    COMPUTE(Pa, xa, ct);
    // phase B: prefetch tile ct+2 into Pa (clamped), compute ct+1 from Pb
    size_t nb2 = (tt + 2 < HT) ? bb + 2048 : bb;
    int ctn2 = (tt + 2 < HT) ? ct + 2 : ct;
    LOADB(Pa, nb2);
    xa = x2b[ctn2 * 16 + c];
    COMPUTE(Pb, xb, ct + 1);
    bb += 2048;
  }
  // ---- parallel exact in-place merge, one pass per row-set (32 rows) ----
#pragma unroll
  for (int pass = 0; pass < NSET; ++pass) {
    // write per-lane sorted lists: row lrow = s*16+q*4+r, list = hf*16+c
#pragma unroll
    for (int r = 0; r < 4; ++r) {
      int lrow = s * 16 + q * 4 + r;
      unsigned* dst = lm + lrow * 289 + (hf * 16 + c) * 9;
#pragma unroll
      for (int p = 0; p < KNN; ++p) dst[p] = best[pass][r][p];
    }
    __syncthreads();
    // level A: 32 rows x 8 mergers, 4 lists each (u64-lift with col-in-tile);
    // result written in place over the consumed region (exclusive ownership).
    {
      int arow = t >> 3, am = t & 7;
      unsigned* base = lm + arow * 289;
      const unsigned* l0 = base + (am * 4) * 9;
      u64 fin[KNN];
#pragma unroll
      for (int p = 0; p < KNN; ++p)
        fin[p] = (((u64)l0[p]) << 4) | (unsigned)((am * 4) & 15);
      for (int d = 1; d < 4; ++d) {
        const unsigned* ld = base + (am * 4 + d) * 9;
        unsigned cb = (unsigned)((am * 4 + d) & 15);
        for (int p = 0; p < KNN; ++p) {
          u64 ckk = (((u64)ld[p]) << 4) | cb;
          if (ckk >= fin[KNN - 1]) break;  // ld sorted ascending
#pragma unroll
          for (int p2 = 0; p2 < KNN; ++p2) {
            u64 ob = fin[p2];
            bool ex = ob < ckk;
            fin[p2] = ex ? ob : ckk;
            ckk = ex ? ckk : ob;
          }
        }
      }
      unsigned* dst = base + (am * 4) * 9;  // lo/hi u32 pairs (289 is odd)
#pragma unroll
      for (int p = 0; p < KNN; ++p) {
        dst[2 * p] = (unsigned)fin[p];
        dst[2 * p + 1] = (unsigned)(fin[p] >> 32);
      }
    }
    __syncthreads();
    // level B: 32 rows x 2 mergers, 4 level-A results each, in place
    if (t < 64) {
      int brow = t >> 1, bm = t & 1;
      unsigned* base = lm + brow * 289;
      u64 fin[KNN];
      {
        const unsigned* s0 = base + (bm * 4) * 36;
#pragma unroll
        for (int p = 0; p < KNN; ++p)
          fin[p] = (((u64)s0[2 * p + 1]) << 32) | s0[2 * p];
      }
      for (int d = 1; d < 4; ++d) {
        const unsigned* sd = base + (bm * 4 + d) * 36;
        for (int p = 0; p < KNN; ++p) {
          u64 ckk = (((u64)sd[2 * p + 1]) << 32) | sd[2 * p];
          if (ckk >= fin[KNN - 1]) break;
#pragma unroll
          for (int p2 = 0; p2 < KNN; ++p2) {
            u64 ob = fin[p2];
            bool ex = ob < ckk;
            fin[p2] = ex ? ob : ckk;
            ckk = ex ? ckk : ob;
          }
        }
      }
      unsigned* dst = base + (bm * 4) * 36;
#pragma unroll
      for (int p = 0; p < KNN; ++p) {
        dst[2 * p] = (unsigned)fin[p];
        dst[2 * p + 1] = (unsigned)(fin[p] >> 32);
      }
    }
    __syncthreads();
    // level C: 32 rows, final 2-list merge + decode + emit
    if (t < 32) {
      unsigned* base = lm + t * 289;
      u64 fin[KNN];
#pragma unroll
      for (int p = 0; p < KNN; ++p)
        fin[p] = (((u64)base[2 * p + 1]) << 32) | base[2 * p];
      const unsigned* s1 = base + 144;
      for (int p = 0; p < KNN; ++p) {
        u64 ckk = (((u64)s1[2 * p + 1]) << 32) | s1[2 * p];
        if (ckk >= fin[KNN - 1]) break;
#pragma unroll
        for (int p2 = 0; p2 < KNN; ++p2) {
          u64 ob = fin[p2];
          bool ex = ob < ckk;
          fin[p2] = ex ? ob : ckk;
          ckk = ex ? ckk : ob;
        }
      }
      int row = rb + (t >> 4) * SS + pass * 16 + (t & 15);
      int* ob = g_nbr + ((size_t)b * n + row) * KNN;
#pragma unroll
      for (int p = 0; p < KNN; ++p) {
        int j = (int)((fin[p] >> 4) & 255u) * 16 + (int)(fin[p] & 15u);
        ob[p] = j & (n - 1);
      }
    }
    if (pass + 1 < NSET) __syncthreads();
  }
}

// ---------------- per-node u/v for EdgeConv layer-1 factorization ------------
__global__ __launch_bounds__(256) void uv_kernel(int level,
                                                 const float* __restrict__ w1g,
                                                 const float* __restrict__ b1g) {
  __shared__ float sw1[128 * 96];  // 48 KB
  __shared__ float sb1[96];
  int t = threadIdx.x;
  for (int q = t; q < 128 * 96; q += 256) sw1[q] = w1g[q];
  if (t < 96) sb1[t] = b1g[t];
  __syncthreads();
  const int n = level ? N2 : N1;
  const float* h = level ? g_h2 : g_h1;
  int b = blockIdx.x & 7;
  int nl = (blockIdx.x >> 3) * 64 + (t & 63);
  int c0 = (t >> 6) * 24;  // wave-uniform chunk
  size_t node = (size_t)b * n + nl;
  const float4* h4 = (const float4*)(h + node * HID);
  float hv[HID];
#pragma unroll
  for (int q = 0; q < 16; ++q) {
    float4 vv = h4[q];
    hv[4 * q] = vv.x; hv[4 * q + 1] = vv.y; hv[4 * q + 2] = vv.z; hv[4 * q + 3] = vv.w;
  }
  float ua[24], va[24];
#pragma unroll
  for (int c = 0; c < 24; ++c) { ua[c] = 0.f; va[c] = 0.f; }
  for (int d = 0; d < HID; ++d) {
    float hd = hv[d];
    const float* wt = sw1 + d * 96 + c0;        // wave-uniform -> broadcast
    const float* wb = sw1 + (HID + d) * 96 + c0;
#pragma unroll
    for (int c = 0; c < 24; ++c) {
      ua[c] += hd * wt[c];
      va[c] += hd * wb[c];
    }
  }
  float* ur = g_uu + node * 96 + c0;
  float* vr = g_vv + node * 96 + c0;
#pragma unroll
  for (int c = 0; c < 24; ++c) {
    float uval = ua[c] - va[c] + sb1[c0 + c];
    float vval = va[c];
    ur[c] = uval;
    vr[c] = vval;
    int kk = c0 + c;
    size_t fa = (node >> 4) * 1536 + (size_t)((kk >> 5) * 512 +
                ((kk >> 3) & 3) * 128 + (nl & 15) * 8 + (kk & 7));
    g_uf[fa] = uval;
    g_vf[fa] = vval;
  }
}

// ---------------- MFMA edge messages + max scatter (r17 config) --------------
// Wave = 16 nodes (one frag tile), 4 waves/block: W-frags hoisted once per
// 64 nodes and intra-block wave overlap hides the neighbor-gather latency.
// (r20's 1-wave split re-loaded W-frags 4x and regressed ~100us.)
template <int LEVEL>
__global__ __launch_bounds__(256, 1) void edge_kernel(
    const float* __restrict__ b2g) {
  constexpr int n = LEVEL ? N2 : N1;
  unsigned* ekey = LEVEL ? g_ek2 : g_ek1;
  int b = blockIdx.x & 7;  // XCD swizzle
  int t = threadIdx.x;
  int wv = t >> 6, lane = t & 63;
  int q = lane >> 4, c = lane & 15;
  int base16 = (blockIdx.x >> 3) * 64 + wv * 16;
  int node_c = base16 + c;
  const int* nbb = g_nbr + (size_t)b * n * KNN;
  const float* ub = g_uu + (size_t)b * n * 96;
  const float* vb = g_vv + (size_t)b * n * 96;
  size_t ftile = ((size_t)(b * n + base16) >> 4) * 1536;
  unsigned* eb = ekey + (size_t)b * n * HID;
  short8 W1f[4][3], W2f[4][3];
#pragma unroll
  for (int no = 0; no < 4; ++no)
#pragma unroll
    for (int kc = 0; kc < 3; ++kc) {
      int off = LEVEL * 6144 + ((no * 3 + kc) * 64 + lane) * 8;
      W1f[no][kc] = *(const short8*)(g_wf1 + off);
      W2f[no][kc] = *(const short8*)(g_wf2 + off);
    }
  float biasv[4];
#pragma unroll
  for (int no = 0; no < 4; ++no) biasv[no] = b2g[no * 16 + c];
  float macc[16];
#pragma unroll
  for (int e = 0; e < 16; ++e) macc[e] = -1.0f;
  for (int slot = 0; slot < KNN; ++slot) {
    int jn = nbb[(size_t)node_c * KNN + slot] & (n - 1);
    short8 t1[3], t2[3], r1[3], r2[3];
#pragma unroll
    for (int kc = 0; kc < 3; ++kc) {
      size_t fo = ftile + kc * 512 + lane * 8;
      float4 su0 = *(const float4*)(g_uf + fo);
      float4 su1 = *(const float4*)(g_uf + fo + 4);
      float4 sv0 = *(const float4*)(g_vf + fo);
      float4 sv1 = *(const float4*)(g_vf + fo + 4);
      size_t go = (size_t)jn * 96 + kc * 32 + q * 8;
      float4 gv0 = *(const float4*)(vb + go);
      float4 gv1 = *(const float4*)(vb + go + 4);
      float4 gu0 = *(const float4*)(ub + go);
      float4 gu1 = *(const float4*)(ub + go + 4);
      tv_frag(su0, su1, gv0, gv1, t1[kc], t2[kc]);   // fwd: u_i + v_j
      tv_frag(gu0, gu1, sv0, sv1, r1[kc], r2[kc]);   // rev: u_j + v_i
    }
    f32x4 aF[4], aR[4];
#pragma unroll
    for (int no = 0; no < 4; ++no) {
      aF[no] = (f32x4){0.f, 0.f, 0.f, 0.f};
      aR[no] = (f32x4){0.f, 0.f, 0.f, 0.f};
    }
#pragma unroll
    for (int no = 0; no < 4; ++no)
#pragma unroll
      for (int kc = 0; kc < 3; ++kc) {
        aF[no] = __builtin_amdgcn_mfma_f32_16x16x32_bf16(t1[kc], W1f[no][kc], aF[no], 0, 0, 0);
        aF[no] = __builtin_amdgcn_mfma_f32_16x16x32_bf16(t2[kc], W1f[no][kc], aF[no], 0, 0, 0);
        aF[no] = __builtin_amdgcn_mfma_f32_16x16x32_bf16(t1[kc], W2f[no][kc], aF[no], 0, 0, 0);
        aR[no] = __builtin_amdgcn_mfma_f32_16x16x32_bf16(r1[kc], W1f[no][kc], aR[no], 0, 0, 0);
        aR[no] = __builtin_amdgcn_mfma_f32_16x16x32_bf16(r2[kc], W1f[no][kc], aR[no], 0, 0, 0);
        aR[no] = __builtin_amdgcn_mfma_f32_16x16x32_bf16(r1[kc], W2f[no][kc], aR[no], 0, 0, 0);
      }
#pragma unroll
    for (int r = 0; r < 4; ++r) {
      int jr = nbb[(size_t)(base16 + q * 4 + r) * KNN + slot] & (n - 1);
#pragma unroll
      for (int no = 0; no < 4; ++no) {
        float mv = eluf(aR[no][r] + biasv[no]);
        atomicMax(&eb[(size_t)jr * HID + no * 16 + c], enc_safe(mv));
      }
    }
#pragma unroll
    for (int no = 0; no < 4; ++no)
#pragma unroll
      for (int r = 0; r < 4; ++r)
        macc[no * 4 + r] = fmaxf(macc[no * 4 + r], eluf(aF[no][r] + biasv[no]));
  }
#pragma unroll
  for (int r = 0; r < 4; ++r) {
    size_t ib = (size_t)(base16 + q * 4 + r) * HID;
#pragma unroll
    for (int no = 0; no < 4; ++no)
      atomicMax(&eb[ib + no * 16 + c], enc_safe(macc[no * 4 + r]));
  }
}

// ---------------- pairwise max pool + norms + bf16 splits --------------------
__global__ __launch_bounds__(256) void pool_kernel() {
  int node = blockIdx.x * 256 + threadIdx.x;  // < BATCH*N2
  int b = node >> 11;
  int m = node & (N2 - 1);
  const unsigned* e = g_ek1 + ((size_t)b * N1 + 2 * m) * HID;
  float* hr = g_h2 + (size_t)node * HID;
  float sq = 0.f;
  short s1l[HID], s2l[HID], s3l[HID];
#pragma unroll
  for (int d = 0; d < HID; ++d) {
    float mx = fmaxf(dec_safe(e[d]), dec_safe(e[HID + d]));
    hr[d] = mx;
    sq += mx * mx;
    split3(mx, s1l[d], s2l[d], s3l[d]);
  }
  store_frags(node, s1l, s2l, s3l);
  g_x2n2[node] = sq;
}

// ---------------- global max + output MLP -> FLOAT32 output ------------------
// 256 threads: 4-way row-split scan of g_ek2 + LDS combine.
__global__ __launch_bounds__(256) void final_kernel(
    const float* __restrict__ wo1, const float* __restrict__ bo1,
    const float* __restrict__ wo2, const float* __restrict__ bo2,
    const float* __restrict__ wo3, const float* __restrict__ bo3,
    float* __restrict__ out) {
  __shared__ unsigned red[4][HID];
  __shared__ float g[HID];
  __shared__ float o1s[HID];
  __shared__ float o2s[32];
  int b = blockIdx.x;
  int t = threadIdx.x;  // 0..255
  int grp = t >> 6, d = t & 63;
  const unsigned* e = g_ek2 + (size_t)b * N2 * HID;
  unsigned mk = 0u;
  for (int m = grp; m < N2; m += 4) {
    unsigned qv = e[(size_t)m * HID + d];
    mk = qv > mk ? qv : mk;
  }
  red[grp][d] = mk;
  __syncthreads();
  if (t < HID) {
    unsigned q1 = red[0][t] > red[1][t] ? red[0][t] : red[1][t];
    unsigned q2 = red[2][t] > red[3][t] ? red[2][t] : red[3][t];
    g[t] = dec_safe(q1 > q2 ? q1 : q2);
  }
  __syncthreads();
  if (t < HID) {
    float a1 = bo1[t];
    for (int dd = 0; dd < HID; ++dd) a1 += g[dd] * wo1[dd * HID + t];
    o1s[t] = eluf(a1);
  }
  __syncthreads();
  if (t < 32) {
    float a2 = bo2[t];
    for (int dd = 0; dd < HID; ++dd) a2 += o1s[dd] * wo2[dd * 32 + t];
    o2s[t] = eluf(a2);
  }
  __syncthreads();
  if (t == 0) {
    float acc0 = bo3[0];
    float acc1 = bo3[1];
    for (int dd = 0; dd < 32; ++dd) {
      acc0 += o2s[dd] * wo3[dd * 2 + 0];
      acc1 += o2s[dd] * wo3[dd * 2 + 1];
    }
    float met = fmaxf(acc0, 0.f) + log1pf(expf(-fabsf(acc0)));      // softplus
    float phi = 3.14159265358979f * (2.f / (1.f + expf(-acc1)) - 1.f);
    out[b * 2 + 0] = met;
    out[b * 2 + 1] = phi;
  }
}

extern "C" void kernel_launch(void* const* d_in, const int* in_sizes, int n_in,
                              void* d_out, int out_size, void* d_ws,
                              size_t ws_size, hipStream_t stream) {
  const float* x     = (const float*)d_in[0];
  const float* dnorm = (const float*)d_in[1];
  const float* w_in1 = (const float*)d_in[2];
  const float* b_in1 = (const float*)d_in[3];
  const float* w_in2 = (const float*)d_in[4];
  const float* b_in2 = (const float*)d_in[5];
  const float* w_c1a = (const float*)d_in[6];
  const float* b_c1a = (const float*)d_in[7];
  const float* w_c1b = (const float*)d_in[8];
  const float* b_c1b = (const float*)d_in[9];
  const float* w_c2a = (const float*)d_in[10];
  const float* b_c2a = (const float*)d_in[11];
  const float* w_c2b = (const float*)d_in[12];
  const float* b_c2b = (const float*)d_in[13];
  const float* w_o1  = (const float*)d_in[14];
  const float* b_o1  = (const float*)d_in[15];
  const float* w_o2  = (const float*)d_in[16];
  const float* b_o2  = (const float*)d_in[17];
  const float* w_o3  = (const float*)d_in[18];
  const float* b_o3  = (const float*)d_in[19];

  init_kernel<<<(BATCH * N1 * HID + BATCH * N2 * HID) / 4 / 256, 256, 0,
                stream>>>();
  wfrag_kernel<<<2, 256, 0, stream>>>(w_c1b, w_c2b);
  input_mlp<<<BATCH * N1 / 256, 256, 0, stream>>>(x, dnorm, w_in1, b_in1,
                                                  w_in2, b_in2);
  knn_kernel<0><<<8 * (N1 / 64), 256, 0, stream>>>();   // 64 rows/block
  uv_kernel<<<8 * (N1 / 64), 256, 0, stream>>>(0, w_c1a, b_c1a);
  edge_kernel<0><<<8 * (N1 / 64), 256, 0, stream>>>(b_c1b);
  pool_kernel<<<BATCH * N2 / 256, 256, 0, stream>>>();
  knn_kernel<1><<<8 * (N2 / 32), 256, 0, stream>>>();   // 32 rows/block
  uv_kernel<<<8 * (N2 / 64), 256, 0, stream>>>(1, w_c2a, b_c2a);
  edge_kernel<1><<<8 * (N2 / 64), 256, 0, stream>>>(b_c2b);
  final_kernel<<<BATCH, 256, 0, stream>>>(w_o1, b_o1, w_o2, b_o2, w_o3, b_o3,
                                          (float*)d_out);
}

// Round 9
// 493.500 us; speedup vs baseline: 1.2430x; 1.1429x over previous
//
#include <hip/hip_runtime.h>
#include <hip/hip_bf16.h>

#define BATCH 8
#define N1 4096
#define N2 2048
#define HID 64
#define KNN 8
#define INDIM 10

using u64 = unsigned long long;
using bf16 = __hip_bfloat16;
typedef __attribute__((ext_vector_type(8))) short short8;
typedef __attribute__((ext_vector_type(4))) float f32x4;

// Scratch in static device memory (~115 MB): d_ws size is not guaranteed.
// Every buffer is fully rewritten each call (or re-initialized by init body).
__device__ __align__(256) float    g_h1[BATCH * N1 * HID];
__device__ __align__(256) float    g_h2[BATCH * N2 * HID];
__device__ __align__(256) float    g_x2n[BATCH * N1];
__device__ __align__(256) float    g_x2n2[BATCH * N2];
__device__ __align__(256) int      g_nbr[BATCH * N1 * KNN];
__device__ __align__(256) float    g_uu[BATCH * N1 * 96];
__device__ __align__(256) float    g_vv[BATCH * N1 * 96];
__device__ __align__(256) unsigned g_ek1[BATCH * N1 * HID];
__device__ __align__(256) unsigned g_ek2[BATCH * N2 * HID];
// 3-way bf16 split of h in MFMA FRAGMENT-MAJOR layout (kNN):
// [tile16][chunk(2)][q(4)][c(16)][j(8)] shorts; node i=tile*16+c.
__device__ __align__(256) short    g_f1[BATCH * N1 * HID];
__device__ __align__(256) short    g_f2[BATCH * N1 * HID];
__device__ __align__(256) short    g_f3[BATCH * N1 * HID];
// frag-major f32 copies of u,v for edge MFMA A-prep:
// [tile16][kc(3)][q(4)][c(16)][j(8)] floats, node = tile*16+c, kk=kc*32+q*8+j.
__device__ __align__(256) float    g_uf[BATCH * N1 * 96];
__device__ __align__(256) float    g_vf[BATCH * N1 * 96];
// 2-way bf16 split W2 fragments: [level][no(4)][kc(3)][lane(64)][j(8)]
__device__ __align__(256) short    g_wf1[2 * 4 * 3 * 64 * 8];
__device__ __align__(256) short    g_wf2[2 * 4 * 3 * 64 * 8];

__device__ __forceinline__ float eluf(float x) { return x > 0.f ? x : __expf(x) - 1.f; }
// order-isomorphic float->u32 encoding: a<b  <=>  enc(a)<enc(b) (unsigned)
__device__ __forceinline__ unsigned encf(float f) {
  unsigned u = __float_as_uint(f);
  return u ^ ((unsigned)((int)u >> 31) | 0x80000000u);
}
__device__ __forceinline__ float decf(unsigned k) {
  unsigned u = (k & 0x80000000u) ? (k & 0x7FFFFFFFu) : ~k;
  return __uint_as_float(u);
}
// encf(-1.0f): ELU outputs are strictly > -1 => legal max-identity.
#define ENC_NEG1 0x407FFFFFu
__device__ __forceinline__ unsigned enc_safe(float v) {
  if (!(v == v)) return ENC_NEG1;
  return encf(v);
}
__device__ __forceinline__ float dec_safe(unsigned k) {
  float v = decf(k);
  if (!(v == v)) return -1.0f;
  return fminf(fmaxf(v, -3.0e38f), 3.0e38f);
}
// v_med3_u32: median of three u32. Inserting x into a SORTED ascending list a:
// r[i] = med3(a[i-1], a[i], x)  (r[0] = min(a[0], x)) -- 8 independent ops,
// half the op count of the min/max bubble and no serial dep chain.
__device__ __forceinline__ unsigned umed3(unsigned a, unsigned b, unsigned c) {
  unsigned d;
  asm("v_med3_u32 %0, %1, %2, %3" : "=v"(d) : "v"(a), "v"(b), "v"(c));
  return d;
}
// 3-way bf16 split: v ~= b1 + b2 + b3 (error ~2^-25 relative)
__device__ __forceinline__ void split3(float v, short& b1, short& b2, short& b3) {
  bf16 x1 = __float2bfloat16(v);
  float r1 = v - __bfloat162float(x1);
  bf16 x2 = __float2bfloat16(r1);
  float r2 = r1 - __bfloat162float(x2);
  bf16 x3 = __float2bfloat16(r2);
  b1 = *(short*)&x1; b2 = *(short*)&x2; b3 = *(short*)&x3;
}
// 2-way bf16 split
__device__ __forceinline__ void split2(float v, short& b1, short& b2) {
  bf16 x1 = __float2bfloat16(v);
  float r1 = v - __bfloat162float(x1);
  bf16 x2 = __float2bfloat16(r1);
  b1 = *(short*)&x1; b2 = *(short*)&x2;
}
// write one node's 64 splits into kNN fragment-major layout
__device__ __forceinline__ void store_frags(int node, const short* s1,
                                            const short* s2, const short* s3) {
  size_t tb = ((size_t)(node >> 4)) * 1024 + (node & 15) * 8;
#pragma unroll
  for (int chunk = 0; chunk < 2; ++chunk) {
#pragma unroll
    for (int q = 0; q < 4; ++q) {
      size_t a = tb + chunk * 512 + q * 128;
      int k = chunk * 32 + q * 8;
      *(short8*)(g_f1 + a) = *(const short8*)(s1 + k);
      *(short8*)(g_f2 + a) = *(const short8*)(s2 + k);
      *(short8*)(g_f3 + a) = *(const short8*)(s3 + k);
    }
  }
}
// elu(a+b) for 8 floats -> 2-way split short8 frags
__device__ __forceinline__ void tv_frag(float4 a0, float4 a1, float4 b0,
                                        float4 b1, short8& s1, short8& s2) {
  float v[8] = {a0.x + b0.x, a0.y + b0.y, a0.z + b0.z, a0.w + b0.w,
                a1.x + b1.x, a1.y + b1.y, a1.z + b1.z, a1.w + b1.w};
#pragma unroll
  for (int e = 0; e < 8; ++e) {
    float t = eluf(v[e]);
    short p1, p2;
    split2(t, p1, p2);
    s1[e] = p1; s2[e] = p2;
  }
}

// ================= P1: prep = input_mlp (128 blks) + wfrag (2) + init (3072) =
// All three are mutually independent writers (g_h1/g_f*/g_x2n vs g_wf* vs
// g_ek*), so they pack into ONE launch with block-range dispatch. r29: the
// non-knn pipeline portion is ~390us across rounds while its estimated work
// is ~100-150us -- launch overhead + small-grid serialization. 11 -> 7
// launches total.
__global__ __launch_bounds__(256) void prep_kernel(
    const float* __restrict__ x, const float* __restrict__ norm,
    const float* __restrict__ w1g, const float* __restrict__ b1g,
    const float* __restrict__ w2g, const float* __restrict__ b2g,
    const float* __restrict__ wc1b, const float* __restrict__ wc2b) {
  int bid = blockIdx.x;
  int t = threadIdx.x;
  if (bid < 128) {
    // ---- input MLP: x*norm -> 32 (elu) -> 64 (elu) + |h|^2 + splits ----
    __shared__ float sw1[320], sb1[32], sw2[2048], sb2[64], snorm[INDIM];
    for (int q = t; q < 320; q += 256) sw1[q] = w1g[q];
    for (int q = t; q < 2048; q += 256) sw2[q] = w2g[q];
    if (t < 32) sb1[t] = b1g[t];
    if (t < 64) sb2[t] = b2g[t];
    if (t < INDIM) snorm[t] = norm[t];
    __syncthreads();
    int node = bid * 256 + t;  // < BATCH*N1
    float xv[INDIM];
#pragma unroll
    for (int d = 0; d < INDIM; ++d)
      xv[d] = x[(size_t)node * INDIM + d] * snorm[d];
    float t1[32];
#pragma unroll
    for (int c = 0; c < 32; ++c) {
      float acc = sb1[c];
#pragma unroll
      for (int d = 0; d < INDIM; ++d) acc += xv[d] * sw1[d * 32 + c];
      t1[c] = eluf(acc);
    }
    float* hr = g_h1 + (size_t)node * HID;
    float sq = 0.f;
    short s1l[HID], s2l[HID], s3l[HID];
#pragma unroll
    for (int c = 0; c < HID; ++c) {
      float acc = sb2[c];
#pragma unroll
      for (int d = 0; d < 32; ++d) acc += t1[d] * sw2[d * HID + c];
      float v = eluf(acc);
      hr[c] = v;
      sq += v * v;
      split3(v, s1l[c], s2l[c], s3l[c]);
    }
    store_frags(node, s1l, s2l, s3l);
    g_x2n[node] = sq;
  } else if (bid < 130) {
    // ---- W2 -> 2-way-split MFMA B-fragments ----
    int level = bid - 128;
    const float* w = level ? wc2b : wc1b;
    for (int idx = t; idx < 6144; idx += 256) {
      int no = idx / 1536;
      int rem = idx - no * 1536;
      int kc = rem / 512;
      int rem2 = rem - kc * 512;
      int lane = rem2 >> 3;
      int j = rem2 & 7;
      int k = kc * 32 + (lane >> 4) * 8 + j;
      int o = no * 16 + (lane & 15);
      short b1, b2;
      split2(w[k * 64 + o], b1, b2);
      g_wf1[level * 6144 + idx] = b1;
      g_wf2[level * 6144 + idx] = b2;
    }
  } else {
    // ---- init the scatter-max accumulators (3072 blocks, exact) ----
    int tt = (bid - 130) * 256 + t;
    uint4 z = make_uint4(ENC_NEG1, ENC_NEG1, ENC_NEG1, ENC_NEG1);
    const int n1 = BATCH * N1 * HID / 4;
    if (tt < n1) ((uint4*)g_ek1)[tt] = z;
    else ((uint4*)g_ek2)[tt - n1] = z;
  }
}

// ---------------- MFMA Gram-matrix kNN body (r28, unchanged) -----------------
// r28 geometry: grid 8*(N/64 | N/32) blocks of 256 = 2 row-strips x 2 column
// halves, NSET (2|1) 16-row A-tiles per strip; register ping-pong 1-tile-deep
// B-fragment prefetch (155->137.7us); med3 sorted-insert selection; in-place
// 3-level LDS merge (37 KB, 289-stride banking). Occupancy is VGPR-bucket-
// pinned at ~2 waves/SIMD (r21-r27 sweep) -- ILP, not TLP, hides latency.
template <int LEVEL>
__device__ __forceinline__ void knn_body(unsigned* lm) {
  constexpr int n = LEVEL ? N2 : N1;
  constexpr int NT = n / 16;           // column tiles in batch
  constexpr int HT = NT / 2;           // tiles per column half (even: 128/64)
  constexpr int NSET = LEVEL ? 1 : 2;  // 16-row A-tiles per strip
  constexpr int SS = NSET * 16;        // rows per strip

  int b = blockIdx.x & 7;              // XCD-friendly batch swizzle
  int rb = (blockIdx.x >> 3) * (2 * SS);
  int t = threadIdx.x;
  int wv = t >> 6, lane = t & 63;
  int s = wv >> 1, hf = wv & 1;        // row strip / column half
  int q = lane >> 4, c = lane & 15;
  const float* __restrict__ x2b = (LEVEL ? g_x2n2 : g_x2n) + (size_t)b * n;
  size_t abase = ((size_t)((b * n + rb + s * SS) >> 4)) * 1024 + lane * 8;
  short8 A1a[NSET], A1b[NSET], A2a[NSET], A2b[NSET], A3a[NSET], A3b[NSET];
#pragma unroll
  for (int e = 0; e < NSET; ++e) {
    size_t ab = abase + (size_t)e * 1024;
    A1a[e] = *(const short8*)(g_f1 + ab);
    A1b[e] = *(const short8*)(g_f1 + ab + 512);
    A2a[e] = *(const short8*)(g_f2 + ab);
    A2b[e] = *(const short8*)(g_f2 + ab + 512);
    A3a[e] = *(const short8*)(g_f3 + ab);
    A3b[e] = *(const short8*)(g_f3 + ab + 512);
  }
  unsigned best[NSET][4][KNN];
#pragma unroll
  for (int e = 0; e < NSET; ++e)
#pragma unroll
    for (int r = 0; r < 4; ++r)
#pragma unroll
      for (int p = 0; p < KNN; ++p) best[e][r][p] = 0xFFFFFFFFu;
  const int ct0 = hf * HT;
  const int selftile = (rb + s * SS) >> 4;  // + e = only tile with cb==i
  const f32x4 zero = {0.f, 0.f, 0.f, 0.f};
  size_t bb = ((size_t)(b * n) >> 4) * 1024 + (size_t)ct0 * 1024 + lane * 8;

  // ping-pong B-fragment buffers: P[0..5] = B1a,B1b,B2a,B2b,B3a,B3b
  short8 Pa[6], Pb[6];
  float xa, xb;
  auto LOADB = [&](short8* P, size_t addr) {
    P[0] = *(const short8*)(g_f1 + addr);
    P[1] = *(const short8*)(g_f1 + addr + 512);
    P[2] = *(const short8*)(g_f2 + addr);
    P[3] = *(const short8*)(g_f2 + addr + 512);
    P[4] = *(const short8*)(g_f3 + addr);
    P[5] = *(const short8*)(g_f3 + addr + 512);
  };
  auto COMPUTE = [&](const short8* P, float x2c, int ct) {
#pragma unroll
    for (int e = 0; e < NSET; ++e) {
      f32x4 acc0 = __builtin_amdgcn_mfma_f32_16x16x32_bf16(A1a[e], P[0], zero, 0, 0, 0);
      f32x4 acc1 = __builtin_amdgcn_mfma_f32_16x16x32_bf16(A1b[e], P[1], zero, 0, 0, 0);
      acc0 = __builtin_amdgcn_mfma_f32_16x16x32_bf16(A1a[e], P[2], acc0, 0, 0, 0);
      acc1 = __builtin_amdgcn_mfma_f32_16x16x32_bf16(A1b[e], P[3], acc1, 0, 0, 0);
      acc0 = __builtin_amdgcn_mfma_f32_16x16x32_bf16(A2a[e], P[0], acc0, 0, 0, 0);
      acc1 = __builtin_amdgcn_mfma_f32_16x16x32_bf16(A2b[e], P[1], acc1, 0, 0, 0);
      acc0 = __builtin_amdgcn_mfma_f32_16x16x32_bf16(A1a[e], P[4], acc0, 0, 0, 0);
      acc1 = __builtin_amdgcn_mfma_f32_16x16x32_bf16(A1b[e], P[5], acc1, 0, 0, 0);
      acc0 = __builtin_amdgcn_mfma_f32_16x16x32_bf16(A2a[e], P[2], acc0, 0, 0, 0);
      acc1 = __builtin_amdgcn_mfma_f32_16x16x32_bf16(A2b[e], P[3], acc1, 0, 0, 0);
      acc0 = __builtin_amdgcn_mfma_f32_16x16x32_bf16(A3a[e], P[0], acc0, 0, 0, 0);
      acc1 = __builtin_amdgcn_mfma_f32_16x16x32_bf16(A3b[e], P[1], acc1, 0, 0, 0);
      unsigned ck[4];
#pragma unroll
      for (int r = 0; r < 4; ++r) {
        float sm2 = acc0[r] + acc1[r];
        float dd = __builtin_fmaf(-2.f, sm2, x2c);  // x2r dropped: row-const
        ck[r] = (encf(dd) & 0xFFFFFF00u) | (unsigned)ct;
      }
      if (ct == selftile + e) {  // wave-uniform: self col only in this tile
#pragma unroll
        for (int r = 0; r < 4; ++r)
          if (c == q * 4 + r) ck[r] = 0xFFFFFFFFu;
      }
#pragma unroll
      for (int r = 0; r < 4; ++r) {
        unsigned x = ck[r];
#pragma unroll
        for (int p = KNN - 1; p >= 1; --p)
          best[e][r][p] = umed3(best[e][r][p - 1], best[e][r][p], x);
        best[e][r][0] = min(best[e][r][0], x);
      }
    }
  };

  LOADB(Pa, bb);
  xa = x2b[ct0 * 16 + c];
  for (int tt = 0; tt < HT; tt += 2) {
    int ct = ct0 + tt;
    // phase A: prefetch tile ct+1 into Pb, compute tile ct from Pa
    LOADB(Pb, bb + 1024);
    xb = x2b[(ct + 1) * 16 + c];
    COMPUTE(Pa, xa, ct);
    // phase B: prefetch tile ct+2 into Pa (clamped), compute ct+1 from Pb
    size_t nb2 = (tt + 2 < HT) ? bb + 2048 : bb;
    int ctn2 = (tt + 2 < HT) ? ct + 2 : ct;
    LOADB(Pa, nb2);
    xa = x2b[ctn2 * 16 + c];
    COMPUTE(Pb, xb, ct + 1);
    bb += 2048;
  }
  // ---- parallel exact in-place merge, one pass per row-set (32 rows) ----
#pragma unroll
  for (int pass = 0; pass < NSET; ++pass) {
    // write per-lane sorted lists: row lrow = s*16+q*4+r, list = hf*16+c
#pragma unroll
    for (int r = 0; r < 4; ++r) {
      int lrow = s * 16 + q * 4 + r;
      unsigned* dst = lm + lrow * 289 + (hf * 16 + c) * 9;
#pragma unroll
      for (int p = 0; p < KNN; ++p) dst[p] = best[pass][r][p];
    }
    __syncthreads();
    // level A: 32 rows x 8 mergers, 4 lists each (u64-lift with col-in-tile);
    // result written in place over the consumed region (exclusive ownership).
    {
      int arow = t >> 3, am = t & 7;
      unsigned* base = lm + arow * 289;
      const unsigned* l0 = base + (am * 4) * 9;
      u64 fin[KNN];
#pragma unroll
      for (int p = 0; p < KNN; ++p)
        fin[p] = (((u64)l0[p]) << 4) | (unsigned)((am * 4) & 15);
      for (int d = 1; d < 4; ++d) {
        const unsigned* ld = base + (am * 4 + d) * 9;
        unsigned cb = (unsigned)((am * 4 + d) & 15);
        for (int p = 0; p < KNN; ++p) {
          u64 ckk = (((u64)ld[p]) << 4) | cb;
          if (ckk >= fin[KNN - 1]) break;  // ld sorted ascending
#pragma unroll
          for (int p2 = 0; p2 < KNN; ++p2) {
            u64 ob = fin[p2];
            bool ex = ob < ckk;
            fin[p2] = ex ? ob : ckk;
            ckk = ex ? ckk : ob;
          }
        }
      }
      unsigned* dst = base + (am * 4) * 9;  // lo/hi u32 pairs (289 is odd)
#pragma unroll
      for (int p = 0; p < KNN; ++p) {
        dst[2 * p] = (unsigned)fin[p];
        dst[2 * p + 1] = (unsigned)(fin[p] >> 32);
      }
    }
    __syncthreads();
    // level B: 32 rows x 2 mergers, 4 level-A results each, in place
    if (t < 64) {
      int brow = t >> 1, bm = t & 1;
      unsigned* base = lm + brow * 289;
      u64 fin[KNN];
      {
        const unsigned* s0 = base + (bm * 4) * 36;
#pragma unroll
        for (int p = 0; p < KNN; ++p)
          fin[p] = (((u64)s0[2 * p + 1]) << 32) | s0[2 * p];
      }
      for (int d = 1; d < 4; ++d) {
        const unsigned* sd = base + (bm * 4 + d) * 36;
        for (int p = 0; p < KNN; ++p) {
          u64 ckk = (((u64)sd[2 * p + 1]) << 32) | sd[2 * p];
          if (ckk >= fin[KNN - 1]) break;
#pragma unroll
          for (int p2 = 0; p2 < KNN; ++p2) {
            u64 ob = fin[p2];
            bool ex = ob < ckk;
            fin[p2] = ex ? ob : ckk;
            ckk = ex ? ckk : ob;
          }
        }
      }
      unsigned* dst = base + (bm * 4) * 36;
#pragma unroll
      for (int p = 0; p < KNN; ++p) {
        dst[2 * p] = (unsigned)fin[p];
        dst[2 * p + 1] = (unsigned)(fin[p] >> 32);
      }
    }
    __syncthreads();
    // level C: 32 rows, final 2-list merge + decode + emit
    if (t < 32) {
      unsigned* base = lm + t * 289;
      u64 fin[KNN];
#pragma unroll
      for (int p = 0; p < KNN; ++p)
        fin[p] = (((u64)base[2 * p + 1]) << 32) | base[2 * p];
      const unsigned* s1 = base + 144;
      for (int p = 0; p < KNN; ++p) {
        u64 ckk = (((u64)s1[2 * p + 1]) << 32) | s1[2 * p];
        if (ckk >= fin[KNN - 1]) break;
#pragma unroll
        for (int p2 = 0; p2 < KNN; ++p2) {
          u64 ob = fin[p2];
          bool ex = ob < ckk;
          fin[p2] = ex ? ob : ckk;
          ckk = ex ? ckk : ob;
        }
      }
      int row = rb + (t >> 4) * SS + pass * 16 + (t & 15);
      int* ob = g_nbr + ((size_t)b * n + row) * KNN;
#pragma unroll
      for (int p = 0; p < KNN; ++p) {
        int j = (int)((fin[p] >> 4) & 255u) * 16 + (int)(fin[p] & 15u);
        ob[p] = j & (n - 1);
      }
    }
    if (pass + 1 < NSET) __syncthreads();
  }
}

// ---------------- per-node u/v body for EdgeConv layer-1 factorization -------
// r29: hv[64] register array removed (streams float4s with 1-deep prefetch)
// so the FUSED kernel's regalloc stays in knn's <=128 VGPR bucket.
template <int LEVEL>
__device__ __forceinline__ void uv_body(float* sw1, float* sb1, int ub,
                                        const float* __restrict__ w1g,
                                        const float* __restrict__ b1g) {
  int t = threadIdx.x;
  for (int q = t; q < 128 * 96; q += 256) sw1[q] = w1g[q];
  if (t < 96) sb1[t] = b1g[t];
  __syncthreads();
  const int n = LEVEL ? N2 : N1;
  const float* h = LEVEL ? g_h2 : g_h1;
  int b = ub & 7;
  int nl = (ub >> 3) * 64 + (t & 63);
  int c0 = (t >> 6) * 24;  // wave-uniform chunk
  size_t node = (size_t)b * n + nl;
  const float4* h4 = (const float4*)(h + node * HID);
  float ua[24], va[24];
#pragma unroll
  for (int c = 0; c < 24; ++c) { ua[c] = 0.f; va[c] = 0.f; }
  float4 vv = h4[0];
  for (int qd = 0; qd < 16; ++qd) {
    float4 cur = vv;
    if (qd < 15) vv = h4[qd + 1];
    float el[4] = {cur.x, cur.y, cur.z, cur.w};
#pragma unroll
    for (int j = 0; j < 4; ++j) {
      int d = qd * 4 + j;
      float hd = el[j];
      const float* wt = sw1 + d * 96 + c0;        // wave-uniform -> broadcast
      const float* wb = sw1 + (HID + d) * 96 + c0;
#pragma unroll
      for (int c = 0; c < 24; ++c) {
        ua[c] += hd * wt[c];
        va[c] += hd * wb[c];
      }
    }
  }
  float* ur = g_uu + node * 96 + c0;
  float* vr = g_vv + node * 96 + c0;
#pragma unroll
  for (int c = 0; c < 24; ++c) {
    float uval = ua[c] - va[c] + sb1[c0 + c];
    float vval = va[c];
    ur[c] = uval;
    vr[c] = vval;
    int kk = c0 + c;
    size_t fa = (node >> 4) * 1536 + (size_t)((kk >> 5) * 512 +
                ((kk >> 3) & 3) * 128 + (nl & 15) * 8 + (kk & 7));
    g_uf[fa] = uval;
    g_vf[fa] = vval;
  }
}

// ================= P2/P3: fused kNN + uv (independent after prep/pool) =======
// knn blocks first (long pole), uv blocks fill remaining CU slots and run in
// knn's shadow (LDS union 49.5 KB -> 3 blocks/CU; knn sustains ~2).
template <int LEVEL>
__global__ __launch_bounds__(256, 2) void knuv_kernel(
    const float* __restrict__ w1g, const float* __restrict__ b1g) {
  constexpr int KB = LEVEL ? (8 * (N2 / 32)) : (8 * (N1 / 64));  // 512 both
  __shared__ __align__(16) unsigned char smem[49536];
  if ((int)blockIdx.x < KB) {
    knn_body<LEVEL>((unsigned*)smem);
  } else {
    uv_body<LEVEL>((float*)smem, (float*)(smem + 49152),
                   (int)blockIdx.x - KB, w1g, b1g);
  }
}

// ---------------- MFMA edge messages + max scatter (r17 config) --------------
// Wave = 16 nodes (one frag tile), 4 waves/block: W-frags hoisted once per
// 64 nodes and intra-block wave overlap hides the neighbor-gather latency.
// (r20's 1-wave split re-loaded W-frags 4x and regressed ~100us.)
template <int LEVEL>
__global__ __launch_bounds__(256, 1) void edge_kernel(
    const float* __restrict__ b2g) {
  constexpr int n = LEVEL ? N2 : N1;
  unsigned* ekey = LEVEL ? g_ek2 : g_ek1;
  int b = blockIdx.x & 7;  // XCD swizzle
  int t = threadIdx.x;
  int wv = t >> 6, lane = t & 63;
  int q = lane >> 4, c = lane & 15;
  int base16 = (blockIdx.x >> 3) * 64 + wv * 16;
  int node_c = base16 + c;
  const int* nbb = g_nbr + (size_t)b * n * KNN;
  const float* ub = g_uu + (size_t)b * n * 96;
  const float* vb = g_vv + (size_t)b * n * 96;
  size_t ftile = ((size_t)(b * n + base16) >> 4) * 1536;
  unsigned* eb = ekey + (size_t)b * n * HID;
  short8 W1f[4][3], W2f[4][3];
#pragma unroll
  for (int no = 0; no < 4; ++no)
#pragma unroll
    for (int kc = 0; kc < 3; ++kc) {
      int off = LEVEL * 6144 + ((no * 3 + kc) * 64 + lane) * 8;
      W1f[no][kc] = *(const short8*)(g_wf1 + off);
      W2f[no][kc] = *(const short8*)(g_wf2 + off);
    }
  float biasv[4];
#pragma unroll
  for (int no = 0; no < 4; ++no) biasv[no] = b2g[no * 16 + c];
  float macc[16];
#pragma unroll
  for (int e = 0; e < 16; ++e) macc[e] = -1.0f;
  for (int slot = 0; slot < KNN; ++slot) {
    int jn = nbb[(size_t)node_c * KNN + slot] & (n - 1);
    short8 t1[3], t2[3], r1[3], r2[3];
#pragma unroll
    for (int kc = 0; kc < 3; ++kc) {
      size_t fo = ftile + kc * 512 + lane * 8;
      float4 su0 = *(const float4*)(g_uf + fo);
      float4 su1 = *(const float4*)(g_uf + fo + 4);
      float4 sv0 = *(const float4*)(g_vf + fo);
      float4 sv1 = *(const float4*)(g_vf + fo + 4);
      size_t go = (size_t)jn * 96 + kc * 32 + q * 8;
      float4 gv0 = *(const float4*)(vb + go);
      float4 gv1 = *(const float4*)(vb + go + 4);
      float4 gu0 = *(const float4*)(ub + go);
      float4 gu1 = *(const float4*)(ub + go + 4);
      tv_frag(su0, su1, gv0, gv1, t1[kc], t2[kc]);   // fwd: u_i + v_j
      tv_frag(gu0, gu1, sv0, sv1, r1[kc], r2[kc]);   // rev: u_j + v_i
    }
    f32x4 aF[4], aR[4];
#pragma unroll
    for (int no = 0; no < 4; ++no) {
      aF[no] = (f32x4){0.f, 0.f, 0.f, 0.f};
      aR[no] = (f32x4){0.f, 0.f, 0.f, 0.f};
    }
#pragma unroll
    for (int no = 0; no < 4; ++no)
#pragma unroll
      for (int kc = 0; kc < 3; ++kc) {
        aF[no] = __builtin_amdgcn_mfma_f32_16x16x32_bf16(t1[kc], W1f[no][kc], aF[no], 0, 0, 0);
        aF[no] = __builtin_amdgcn_mfma_f32_16x16x32_bf16(t2[kc], W1f[no][kc], aF[no], 0, 0, 0);
        aF[no] = __builtin_amdgcn_mfma_f32_16x16x32_bf16(t1[kc], W2f[no][kc], aF[no], 0, 0, 0);
        aR[no] = __builtin_amdgcn_mfma_f32_16x16x32_bf16(r1[kc], W1f[no][kc], aR[no], 0, 0, 0);
        aR[no] = __builtin_amdgcn_mfma_f32_16x16x32_bf16(r2[kc], W1f[no][kc], aR[no], 0, 0, 0);
        aR[no] = __builtin_amdgcn_mfma_f32_16x16x32_bf16(r1[kc], W2f[no][kc], aR[no], 0, 0, 0);
      }
#pragma unroll
    for (int r = 0; r < 4; ++r) {
      int jr = nbb[(size_t)(base16 + q * 4 + r) * KNN + slot] & (n - 1);
#pragma unroll
      for (int no = 0; no < 4; ++no) {
        float mv = eluf(aR[no][r] + biasv[no]);
        atomicMax(&eb[(size_t)jr * HID + no * 16 + c], enc_safe(mv));
      }
    }
#pragma unroll
    for (int no = 0; no < 4; ++no)
#pragma unroll
      for (int r = 0; r < 4; ++r)
        macc[no * 4 + r] = fmaxf(macc[no * 4 + r], eluf(aF[no][r] + biasv[no]));
  }
#pragma unroll
  for (int r = 0; r < 4; ++r) {
    size_t ib = (size_t)(base16 + q * 4 + r) * HID;
#pragma unroll
    for (int no = 0; no < 4; ++no)
      atomicMax(&eb[ib + no * 16 + c], enc_safe(macc[no * 4 + r]));
  }
}

// ---------------- pairwise max pool + norms + bf16 splits --------------------
__global__ __launch_bounds__(256) void pool_kernel() {
  int node = blockIdx.x * 256 + threadIdx.x;  // < BATCH*N2
  int b = node >> 11;
  int m = node & (N2 - 1);
  const unsigned* e = g_ek1 + ((size_t)b * N1 + 2 * m) * HID;
  float* hr = g_h2 + (size_t)node * HID;
  float sq = 0.f;
  short s1l[HID], s2l[HID], s3l[HID];
#pragma unroll
  for (int d = 0; d < HID; ++d) {
    float mx = fmaxf(dec_safe(e[d]), dec_safe(e[HID + d]));
    hr[d] = mx;
    sq += mx * mx;
    split3(mx, s1l[d], s2l[d], s3l[d]);
  }
  store_frags(node, s1l, s2l, s3l);
  g_x2n2[node] = sq;
}

// ---------------- global max + output MLP -> FLOAT32 output ------------------
// 256 threads: 4-way row-split scan of g_ek2 + LDS combine.
__global__ __launch_bounds__(256) void final_kernel(
    const float* __restrict__ wo1, const float* __restrict__ bo1,
    const float* __restrict__ wo2, const float* __restrict__ bo2,
    const float* __restrict__ wo3, const float* __restrict__ bo3,
    float* __restrict__ out) {
  __shared__ unsigned red[4][HID];
  __shared__ float g[HID];
  __shared__ float o1s[HID];
  __shared__ float o2s[32];
  int b = blockIdx.x;
  int t = threadIdx.x;  // 0..255
  int grp = t >> 6, d = t & 63;
  const unsigned* e = g_ek2 + (size_t)b * N2 * HID;
  unsigned mk = 0u;
  for (int m = grp; m < N2; m += 4) {
    unsigned qv = e[(size_t)m * HID + d];
    mk = qv > mk ? qv : mk;
  }
  red[grp][d] = mk;
  __syncthreads();
  if (t < HID) {
    unsigned q1 = red[0][t] > red[1][t] ? red[0][t] : red[1][t];
    unsigned q2 = red[2][t] > red[3][t] ? red[2][t] : red[3][t];
    g[t] = dec_safe(q1 > q2 ? q1 : q2);
  }
  __syncthreads();
  if (t < HID) {
    float a1 = bo1[t];
    for (int dd = 0; dd < HID; ++dd) a1 += g[dd] * wo1[dd * HID + t];
    o1s[t] = eluf(a1);
  }
  __syncthreads();
  if (t < 32) {
    float a2 = bo2[t];
    for (int dd = 0; dd < HID; ++dd) a2 += o1s[dd] * wo2[dd * 32 + t];
    o2s[t] = eluf(a2);
  }
  __syncthreads();
  if (t == 0) {
    float acc0 = bo3[0];
    float acc1 = bo3[1];
    for (int dd = 0; dd < 32; ++dd) {
      acc0 += o2s[dd] * wo3[dd * 2 + 0];
      acc1 += o2s[dd] * wo3[dd * 2 + 1];
    }
    float met = fmaxf(acc0, 0.f) + log1pf(expf(-fabsf(acc0)));      // softplus
    float phi = 3.14159265358979f * (2.f / (1.f + expf(-acc1)) - 1.f);
    out[b * 2 + 0] = met;
    out[b * 2 + 1] = phi;
  }
}

extern "C" void kernel_launch(void* const* d_in, const int* in_sizes, int n_in,
                              void* d_out, int out_size, void* d_ws,
                              size_t ws_size, hipStream_t stream) {
  const float* x     = (const float*)d_in[0];
  const float* dnorm = (const float*)d_in[1];
  const float* w_in1 = (const float*)d_in[2];
  const float* b_in1 = (const float*)d_in[3];
  const float* w_in2 = (const float*)d_in[4];
  const float* b_in2 = (const float*)d_in[5];
  const float* w_c1a = (const float*)d_in[6];
  const float* b_c1a = (const float*)d_in[7];
  const float* w_c1b = (const float*)d_in[8];
  const float* b_c1b = (const float*)d_in[9];
  const float* w_c2a = (const float*)d_in[10];
  const float* b_c2a = (const float*)d_in[11];
  const float* w_c2b = (const float*)d_in[12];
  const float* b_c2b = (const float*)d_in[13];
  const float* w_o1  = (const float*)d_in[14];
  const float* b_o1  = (const float*)d_in[15];
  const float* w_o2  = (const float*)d_in[16];
  const float* b_o2  = (const float*)d_in[17];
  const float* w_o3  = (const float*)d_in[18];
  const float* b_o3  = (const float*)d_in[19];

  // P1: input_mlp (128) + wfrag (2) + init (3072)
  prep_kernel<<<3202, 256, 0, stream>>>(x, dnorm, w_in1, b_in1, w_in2, b_in2,
                                        w_c1b, w_c2b);
  // P2: knn<0> (512) + uv<0> (512)
  knuv_kernel<0><<<1024, 256, 0, stream>>>(w_c1a, b_c1a);
  edge_kernel<0><<<8 * (N1 / 64), 256, 0, stream>>>(b_c1b);
  pool_kernel<<<BATCH * N2 / 256, 256, 0, stream>>>();
  // P3: knn<1> (512) + uv<1> (256)
  knuv_kernel<1><<<768, 256, 0, stream>>>(w_c2a, b_c2a);
  edge_kernel<1><<<8 * (N2 / 64), 256, 0, stream>>>(b_c2b);
  final_kernel<<<BATCH, 256, 0, stream>>>(w_o1, b_o1, w_o2, b_o2, w_o3, b_o3,
                                          (float*)d_out);
}